// Round 5
// baseline (634.351 us; speedup 1.0000x reference)
//
#include <hip/hip_runtime.h>
#include <math.h>

typedef unsigned short u16;
typedef float floatx4 __attribute__((ext_vector_type(4)));
typedef __bf16 bf16x8 __attribute__((ext_vector_type(8)));

// Problem constants
#define BB   16
#define TQ   2048   // query length after convs (= 2H)
#define TK   1024   // key rows (= H)
#define HH   1024   // H
#define H2   2048   // 2H
#define QD   80
#define QDP  128    // QD padded to tile width (zero-filled)
#define KD   256
#define NQ   2044
#define NKEY 1024
#define T12N 3072   // t12 table stride per batch (covers s = i+j in [0, 3071))

__device__ __forceinline__ u16 f2bf(float f) {
  unsigned int u = __float_as_uint(f);
  u = u + 0x7fffu + ((u >> 16) & 1u);
  return (u16)(u >> 16);
}
__device__ __forceinline__ float bf2f(u16 s) {
  return __uint_as_float(((unsigned int)s) << 16);
}
__device__ __forceinline__ float tgf(const float* __restrict__ tbl, int x) {
  return tbl[(x < 8191) ? (x < 0 ? 0 : x) : 8191];
}

// ---------------- fused prep: elementwise packs + kl1 row-sums + lgamma table ----------------
// segments (blocks): qc2w 16384 | kl2w 8192 | qlw2 8192 | kcp 3072 | colsum 2048 | lgamma 32
//   => grid 37920
__global__ __launch_bounds__(256) void prep_all_k(
    const float* __restrict__ qc2_w, const float* __restrict__ kl2_w,
    const float* __restrict__ ql_w, const float* __restrict__ kc_w,
    const float* __restrict__ kl1_w,
    u16* __restrict__ qc2w, u16* __restrict__ kl2w, u16* __restrict__ qlw2,
    u16* __restrict__ kcp, float* __restrict__ colsum1, float* __restrict__ tbl)
{
  long b = blockIdx.x;
  const int t = threadIdx.x;
  __shared__ float red[256];
  if (b < 16384) {                       // qc2w: cast (2048x2048)
    long i = b * 256 + t; qc2w[i] = f2bf(qc2_w[i]); return;
  }
  b -= 16384;
  if (b < 8192) {                        // kl2w: cast (1024x2048)
    long i = b * 256 + t; kl2w[i] = f2bf(kl2_w[i]); return;
  }
  b -= 8192;
  if (b < 8192) {                        // qlw2[h,n] = ql_w[h,n+2], n<2044 else 0
    long i = b * 256 + t;
    int n = (int)(i & 2047);
    int h = (int)(i >> 11);
    qlw2[i] = (n < NQ) ? f2bf(ql_w[(long)h * H2 + n + 2]) : (u16)0; return;
  }
  b -= 8192;
  if (b < 3072) {                        // kcp: (1024,256,3)->(1024,768), kk=t*256+d
    long i = b * 256 + t;
    int r = (int)(i % 768);
    int o = (int)(i / 768);
    int tt = r >> 8, d = r & 255;
    kcp[i] = f2bf(kc_w[((long)o * KD + d) * 3 + tt]); return;
  }
  b -= 3072;
  if (b < 2048) {                        // colsum1[o] = sum_n kl1_w[o,n]
    const float* row = kl1_w + b * (long)HH;
    float s = row[t] + row[t + 256] + row[t + 512] + row[t + 768];
    red[t] = s; __syncthreads();
    for (int st = 128; st > 0; st >>= 1) { if (t < st) red[t] += red[t + st]; __syncthreads(); }
    if (!t) colsum1[b] = red[0];
    return;
  }
  b -= 2048;
  { int i = (int)(b * 256 + t); if (i < 8192) tbl[i] = i ? (float)lgamma((double)i) : 0.0f; }
}

// ---------------- tiled transposes (fp32 src -> bf16 dst), 64x64 LDS tiles ----------------
// segments: kl1T 512 | qc1T 64 | qT 1024  => grid 1600
__global__ __launch_bounds__(256) void tpack_k(
    const float* __restrict__ kl1_w, const float* __restrict__ qc1_w,
    const float* __restrict__ query,
    u16* __restrict__ kl1T, u16* __restrict__ qc1T, u16* __restrict__ qT)
{
  __shared__ float tile[64][65];
  int bid = blockIdx.x;
  const int tid = threadIdx.x;
  const int r4 = tid >> 6, c = tid & 63;
  const float* src; u16* dst;
  int sr0, sc0, srcR, srcC, srcStride, dstC;
  if (bid < 512) {                       // kl1T: (2048x1024) -> (1024x2048)
    sr0 = (bid >> 4) * 64; sc0 = (bid & 15) * 64;
    src = kl1_w; srcR = 2048; srcC = 1024; srcStride = 1024;
    dst = kl1T; dstC = 2048;
  } else if ((bid -= 512) < 64) {        // qc1T: (2048x80) -> (128x2048)
    sr0 = (bid >> 1) * 64; sc0 = (bid & 1) * 64;
    src = qc1_w; srcR = 2048; srcC = QD; srcStride = QD;
    dst = qc1T; dstC = 2048;
  } else {                               // qT: per b, (2044x80) -> (128x2048)
    bid -= 64;
    const int b16 = bid >> 6, r = bid & 63;
    sr0 = (r >> 1) * 64; sc0 = (r & 1) * 64;
    src = query + (long)b16 * NQ * QD; srcR = NQ; srcC = QD; srcStride = QD;
    dst = qT + (long)b16 * QDP * 2048; dstC = 2048;
  }
#pragma unroll
  for (int rr = r4; rr < 64; rr += 4) {
    const int gr = sr0 + rr, gc = sc0 + c;
    tile[rr][c] = (gr < srcR && gc < srcC) ? src[(long)gr * srcStride + gc] : 0.f;
  }
  __syncthreads();
#pragma unroll
  for (int rr = r4; rr < 64; rr += 4)
    dst[(long)(sc0 + rr) * dstC + sr0 + c] = f2bf(tile[c][rr]);
}

// ---------------- transposed im2col: kcolT[b][(t,d)][n] = key[b, n+t-1, d] ----------------
// grid 1024: b = bid>>6; tile (m0,d0) of key[b]; writes 3 shifted transposed tiles.
__global__ __launch_bounds__(256) void pack_kcolT_k(const float* __restrict__ key, u16* __restrict__ out) {
  __shared__ float tile[64][65];
  const int bid = blockIdx.x, tid = threadIdx.x;
  const int b = bid >> 6, r = bid & 63;
  const int m0 = (r >> 2) * 64;          // key row (position) tile
  const int d0 = (r & 3) * 64;           // key col (channel) tile
  const int r4 = tid >> 6, c = tid & 63;
#pragma unroll
  for (int rr = r4; rr < 64; rr += 4)
    tile[rr][c] = key[((long)b * NKEY + m0 + rr) * KD + d0 + c];
  __syncthreads();
#pragma unroll
  for (int t = 0; t < 3; t++) {
    const int n = m0 + 1 - t + c;
    if (n >= 0 && n < NKEY) {
#pragma unroll
      for (int rr = r4; rr < 64; rr += 4)
        out[((long)b * 768 + t * 256 + d0 + rr) * NKEY + n] = f2bf(tile[c][rr]);
    }
  }
  // zero the never-written boundary columns: (t=0, n=0) and (t=2, n=1023)
  if (m0 == 0 && c == 0) {
#pragma unroll
    for (int rr = r4; rr < 64; rr += 4)
      out[((long)b * 768 + d0 + rr) * NKEY + 0] = (u16)0;
  }
  if (m0 == 960 && c == 0) {
#pragma unroll
    for (int rr = r4; rr < 64; rr += 4)
      out[((long)b * 768 + 512 + d0 + rr) * NKEY + (NKEY - 1)] = (u16)0;
  }
}

// ---------------- fused bias folds (+ wsum) ----------------
// grid = H2 (bqm) + HH (bkv+wsum) + HH (s1/s0) = 4096
__global__ __launch_bounds__(256) void fold_bias_k(
    const float* __restrict__ qc2_w, const float* __restrict__ qc1_b, const float* __restrict__ qc2_b,
    const float* __restrict__ kl2_w, const float* __restrict__ kl1_b, const float* __restrict__ kl2_b,
    const float* __restrict__ ql_w, const float* __restrict__ colsum1,
    float* __restrict__ bqm, float* __restrict__ bkv, float* __restrict__ s1v, float* __restrict__ s0v,
    float* __restrict__ wsum)
{
  const int bid = blockIdx.x, t = threadIdx.x;
  float s = 0.f, s2 = 0.f;
  if (bid < H2) {
    const float* row = qc2_w + (long)bid * H2;
    for (int k = t; k < H2; k += 256) s += row[k] * qc1_b[k];
  } else if (bid < H2 + HH) {
    const float* row = kl2_w + (long)(bid - H2) * H2;
    for (int k = t; k < H2; k += 256) { const float rv = row[k]; s += rv * kl1_b[k]; s2 += rv * colsum1[k]; }
  } else {
    const float* row = ql_w + (long)(bid - H2 - HH) * H2;
    for (int m = 1 + t; m <= H2 - 2; m += 256) s += row[m];
  }
  __shared__ float red[256];
  __shared__ float red2[256];
  red[t] = s; red2[t] = s2; __syncthreads();
  for (int st = 128; st > 0; st >>= 1) {
    if (t < st) { red[t] += red[t + st]; red2[t] += red2[t + st]; }
    __syncthreads();
  }
  if (!t) {
    if (bid < H2) bqm[bid] = red[0] + qc2_b[bid];
    else if (bid < H2 + HH) { bkv[bid - H2] = red[0] + kl2_b[bid - H2]; wsum[bid - H2] = red2[0]; }
    else {
      int h = bid - H2 - HH;
      s1v[h] = red[0];
      s0v[h] = ql_w[(long)h * H2] + ql_w[(long)h * H2 + H2 - 1];
    }
  }
}

// ---------------- MFMA GEMM: C[b] = A[b] @ B[b]^T (+ biases) ----------------
// Requires: M%128==0, N%128==0, K%32==0, lda/ldb%8==0, 16B-aligned bases.
// kspl: blockIdx.z decodes as (batch = z/kspl, kslice = z%kspl).
// OUTF32 = 1: write fp32 raw; OUTF32 = 0: bf16 with epilogue
//   + colb[n] + rowb[m] + r1m[m]*r1n[n] + r2m[m]*r2n[n]  (null = skip);
//   colb/r1n/r2n advance by batch*sN (per-batch n-side vectors).
__device__ __forceinline__ void gld_lds16(const u16* g, u16* l) {
  __builtin_amdgcn_global_load_lds((const __attribute__((address_space(1))) void*)g,
                                   (__attribute__((address_space(3))) void*)l, 16, 0, 0);
}

template<int OUTF32>
__global__ __launch_bounds__(256) void gemm_bt(
    const u16* __restrict__ A, const u16* __restrict__ B, void* __restrict__ Cv,
    int M, int N, int K, int lda, int ldb, int swap, int kspl,
    long sA, long sB, long sC, long sN,
    const float* __restrict__ colb, const float* __restrict__ rowb,
    const float* __restrict__ r1m, const float* __restrict__ r1n,
    const float* __restrict__ r2m, const float* __restrict__ r2n)
{
  __shared__ __align__(16) u16 As[128 * 32];   // 8 KB
  __shared__ __align__(16) u16 Bs[128 * 32];   // 8 KB
  const int bz = blockIdx.z;
  const int bb_ = (kspl > 1) ? bz / kspl : bz;
  const int ks_ = (kspl > 1) ? bz - bb_ * kspl : 0;
  const int tid  = threadIdx.x;
  const int lane = tid & 63;
  const int wv = tid >> 6;                // wave 0..3
  const int wm = ((tid >> 7) & 1) * 64;   // wave row offset
  const int wn = ((tid >> 6) & 1) * 64;   // wave col offset
  const int m0 = (swap ? blockIdx.x : blockIdx.y) * 128;
  const int n0 = (swap ? blockIdx.y : blockIdx.x) * 128;

  // staging: wave wv covers rows [wv*32, wv*32+32) of both tiles, 2 instrs of 16 rows each
  const int srow = wv * 32 + (lane >> 2);       // lane's source row within tile (first instr)
  const int scol = (lane & 3) << 3;             // 0,8,16,24
  const u16* ga = A + bb_ * sA + (long)ks_ * K + (long)(m0 + srow) * lda + scol;
  const u16* gb = B + bb_ * sB + (long)ks_ * K + (long)(n0 + srow) * ldb + scol;
  u16* la0 = &As[(wv * 32) * 32];
  u16* la1 = &As[(wv * 32 + 16) * 32];
  u16* lb0 = &Bs[(wv * 32) * 32];
  u16* lb1 = &Bs[(wv * 32 + 16) * 32];
  const long a16 = (long)16 * lda;
  const long b16 = (long)16 * ldb;

  floatx4 acc[4][4];
#pragma unroll
  for (int a_ = 0; a_ < 4; a_++)
#pragma unroll
    for (int b_ = 0; b_ < 4; b_++) acc[a_][b_] = (floatx4){0.f, 0.f, 0.f, 0.f};

  const int fr = lane & 15;         // frag row/col within 16
  const int fk = (lane >> 4) << 3;  // frag k offset

  for (int kb = 0; kb < K; kb += 32) {
    gld_lds16(ga,       la0);
    gld_lds16(ga + a16, la1);
    gld_lds16(gb,       lb0);
    gld_lds16(gb + b16, lb1);
    ga += 32; gb += 32;
    __syncthreads();
    bf16x8 af[4], bfr[4];
#pragma unroll
    for (int mi = 0; mi < 4; mi++)
      af[mi] = *reinterpret_cast<const bf16x8*>(&As[(wm + mi * 16 + fr) * 32 + fk]);
#pragma unroll
    for (int ni = 0; ni < 4; ni++)
      bfr[ni] = *reinterpret_cast<const bf16x8*>(&Bs[(wn + ni * 16 + fr) * 32 + fk]);
#pragma unroll
    for (int mi = 0; mi < 4; mi++)
#pragma unroll
      for (int ni = 0; ni < 4; ni++)
        acc[mi][ni] = __builtin_amdgcn_mfma_f32_16x16x32_bf16(af[mi], bfr[ni], acc[mi][ni], 0, 0, 0);
    __syncthreads();
  }

  // epilogue: C/D layout col=lane&15, row=(lane>>4)*4+reg  [m89-verified]
  const int fr4 = (lane >> 4) << 2;
  const int fc  = lane & 15;
  u16*   Cb16 = (u16*)Cv + (long)bz * sC;
  float* Cb32 = (float*)Cv + (long)bz * sC;
  const float* cbp  = colb ? colb + (long)bb_ * sN : nullptr;
  const float* r1np = r1n ? r1n + (long)bb_ * sN : nullptr;
  const float* r2np = r2n ? r2n + (long)bb_ * sN : nullptr;
#pragma unroll
  for (int mi = 0; mi < 4; mi++) {
#pragma unroll
    for (int ni = 0; ni < 4; ni++) {
      const int gm0 = m0 + wm + mi * 16 + fr4;
      const int gn  = n0 + wn + ni * 16 + fc;
      const float cbv  = cbp ? cbp[gn] : 0.f;
      const float r1nv = r1np ? r1np[gn] : 0.f;
      const float r2nv = r2np ? r2np[gn] : 0.f;
#pragma unroll
      for (int rr = 0; rr < 4; rr++) {
        const int gm = gm0 + rr;
        float v = acc[mi][ni][rr] + cbv;
        if (rowb) v += rowb[gm];
        if (r1m)  v += r1m[gm] * r1nv;
        if (r2m)  v += r2m[gm] * r2nv;
        if (OUTF32) Cb32[(long)gm * N + gn] = v;
        else        Cb16[(long)gm * N + gn] = f2bf(v);
      }
    }
  }
}

// ---------------- split-K reduce (batch-major planes) ----------------
__global__ __launch_bounds__(256) void reduce_bk_k(const float* __restrict__ P, u16* __restrict__ out,
                                                   long chunk, int S, long total) {
  long j = ((long)blockIdx.x * 256 + threadIdx.x) * 4;
  if (j >= total) return;
  long b = j / chunk;
  const float* p = P + j + b * chunk * (S - 1);
  float4 s = *reinterpret_cast<const float4*>(p);
  for (int t = 1; t < S; t++) {
    const float4 v = *reinterpret_cast<const float4*>(p + (long)t * chunk);
    s.x += v.x; s.y += v.y; s.z += v.z; s.w += v.w;
  }
  union { u16 h[4]; uint2 u; } o;
  o.h[0] = f2bf(s.x); o.h[1] = f2bf(s.y); o.h[2] = f2bf(s.z); o.h[3] = f2bf(s.w);
  *reinterpret_cast<uint2*>(out + j) = o.u;
}

// ---------------- u-vectors + bias-cross scalars + prior tables ----------------
// blocks 0..2047:      u{0,1,2}[b*128+d] = sum_h TpT[b*128+d, h] * {ql_b, s1v, s0v}[h]
// blocks 2048..2053:   sc[idx] pair dots
// blocks 2054..2117:   c1[b][j]  = lg(j+1) + lg(n_-j+1)
// blocks 2118..2245:   crow[b][i] = lg(n_+1)+lg(i+1+bb)-lg(i+1)-lg(bb)-lg(i+1+n_+bb)
// blocks 2246..2437:   t12[b][s] = lg(s+1) + lg(n_+ql-s)        (s = i+j)
__global__ __launch_bounds__(256) void u_k(
    const u16* __restrict__ TpT, const float* __restrict__ qlb,
    const float* __restrict__ s1, const float* __restrict__ s0,
    const float* __restrict__ tbl, const int* __restrict__ qlens, const int* __restrict__ klens,
    float* __restrict__ u0, float* __restrict__ u1, float* __restrict__ u2,
    float* __restrict__ sc, float* __restrict__ c1,
    float* __restrict__ crow, float* __restrict__ t12)
{
  const int bid = blockIdx.x, t = threadIdx.x;
  __shared__ float4 red[256];
  if (bid < BB * QDP) {
    uint2 v = reinterpret_cast<const uint2*>(TpT + (long)bid * HH)[t];
    float a0 = bf2f((u16)(v.x & 0xffff)), a1 = bf2f((u16)(v.x >> 16));
    float a2 = bf2f((u16)(v.y & 0xffff)), a3 = bf2f((u16)(v.y >> 16));
    float4 q  = reinterpret_cast<const float4*>(qlb)[t];
    float4 w1 = reinterpret_cast<const float4*>(s1)[t];
    float4 w0 = reinterpret_cast<const float4*>(s0)[t];
    float4 s;
    s.x = a0 * q.x  + a1 * q.y  + a2 * q.z  + a3 * q.w;
    s.y = a0 * w1.x + a1 * w1.y + a2 * w1.z + a3 * w1.w;
    s.z = a0 * w0.x + a1 * w0.y + a2 * w0.z + a3 * w0.w;
    s.w = 0.f;
    red[t] = s; __syncthreads();
    for (int st = 128; st > 0; st >>= 1) {
      if (t < st) { red[t].x += red[t + st].x; red[t].y += red[t + st].y; red[t].z += red[t + st].z; }
      __syncthreads();
    }
    if (!t) { u0[bid] = red[0].x; u1[bid] = red[0].y; u2[bid] = red[0].z; }
  } else if (bid < BB * QDP + 6) {
    const int idx = bid - BB * QDP;
    const float* X = (idx == 1 || idx == 5) ? s1 : (idx == 2) ? s0 : qlb;
    const float* Y = (idx == 1 || idx == 3) ? s1 : (idx == 0) ? qlb : s0;
    float4 x = reinterpret_cast<const float4*>(X)[t];
    float4 y = reinterpret_cast<const float4*>(Y)[t];
    float4 s; s.x = x.x * y.x + x.y * y.y + x.z * y.z + x.w * y.w; s.y = s.z = s.w = 0.f;
    red[t] = s; __syncthreads();
    for (int st = 128; st > 0; st >>= 1) {
      if (t < st) red[t].x += red[t + st].x;
      __syncthreads();
    }
    if (!t) sc[idx] = red[0].x;
  } else if (bid < BB * QDP + 6 + 64) {
    const int idx = bid - (BB * QDP + 6);
    const int b = idx >> 2;
    const int j = ((idx & 3) << 8) | t;
    const int kl = klens[b];
    const int n_ = (kl - 1 > 0) ? kl - 1 : 0;
    c1[b * TK + j] = tgf(tbl, j + 1) + tgf(tbl, n_ - j + 1);
  } else if (bid < BB * QDP + 6 + 64 + 128) {
    const int idx = bid - (BB * QDP + 6 + 64);
    const int b = idx >> 3;
    const int i = ((idx & 7) << 8) | t;
    const int ql = qlens[b], kl = klens[b];
    const int n_ = (kl - 1 > 0) ? kl - 1 : 0;
    const int bb = (ql - i > 1) ? ql - i : 1;
    crow[b * TQ + i] = tgf(tbl, n_ + 1) + tgf(tbl, i + 1 + bb) - tgf(tbl, i + 1)
                     - tgf(tbl, bb) - tgf(tbl, i + 1 + n_ + bb);
  } else {
    const int idx = bid - (BB * QDP + 6 + 64 + 128);
    const int b = idx / 12;
    const int s = (idx - b * 12) * 256 + t;
    const int ql = qlens[b], kl = klens[b];
    const int n_ = (kl - 1 > 0) ? kl - 1 : 0;
    t12[b * T12N + s] = tgf(tbl, s + 1) + tgf(tbl, n_ + ql - s);
  }
}

// ---------------- qn via Gram quadratic form ----------------
__global__ __launch_bounds__(256) void qn_k(
    const u16* __restrict__ Wq, const float* __restrict__ WqG,
    const float* __restrict__ u0, const float* __restrict__ u1, const float* __restrict__ u2,
    const float* __restrict__ bqm, const float* __restrict__ qc2_b,
    const float* __restrict__ sc, float* __restrict__ qn)
{
  const int bx = blockIdx.x, t = threadIdx.x;
  const int b = bx >> 10;
  const int i = ((bx & 1023) << 1) | (t >> 7);
  const int d = t & 127;
  const float w  = bf2f(Wq[(long)i * QDP + d]);
  const float g  = WqG[((long)b * H2 + i) * QDP + d];
  const float bq = bqm[i], q2 = qc2_b[i];
  const float uu = u0[b * QDP + d] + bq * u1[b * QDP + d] + q2 * u2[b * QDP + d];
  __shared__ float red[256];
  red[t] = w * (g + 2.f * uu); __syncthreads();
  for (int s = 64; s > 0; s >>= 1) { if ((t & 127) < s) red[t] += red[t + s]; __syncthreads(); }
  if (d == 0) {
    const float cst = sc[0] + bq * bq * sc[1] + q2 * q2 * sc[2]
                    + 2.f * (bq * sc[3] + q2 * sc[4] + bq * q2 * sc[5]);
    qn[b * TQ + i] = red[t] + cst;
  }
}

// ---------------- K3 row norms + the three per-row bias dots ----------------
__global__ __launch_bounds__(256) void rownormk_k(
    const u16* __restrict__ K3, const float* __restrict__ qlb,
    const float* __restrict__ s1, const float* __restrict__ s0,
    float* __restrict__ kn, float* __restrict__ yb, float* __restrict__ y1, float* __restrict__ y0)
{
  const long r = blockIdx.x;
  const int t = threadIdx.x;
  uint2 v = reinterpret_cast<const uint2*>(K3 + r * HH)[t];
  float a0 = bf2f((u16)(v.x & 0xffff)), a1 = bf2f((u16)(v.x >> 16));
  float a2 = bf2f((u16)(v.y & 0xffff)), a3 = bf2f((u16)(v.y >> 16));
  float4 q  = reinterpret_cast<const float4*>(qlb)[t];
  float4 w1 = reinterpret_cast<const float4*>(s1)[t];
  float4 w0 = reinterpret_cast<const float4*>(s0)[t];
  float4 s;
  s.x = a0 * a0   + a1 * a1   + a2 * a2   + a3 * a3;
  s.y = a0 * q.x  + a1 * q.y  + a2 * q.z  + a3 * q.w;
  s.z = a0 * w1.x + a1 * w1.y + a2 * w1.z + a3 * w1.w;
  s.w = a0 * w0.x + a1 * w0.y + a2 * w0.z + a3 * w0.w;
  __shared__ float4 red[256];
  red[t] = s; __syncthreads();
  for (int st = 128; st > 0; st >>= 1) {
    if (t < st) {
      red[t].x += red[t + st].x; red[t].y += red[t + st].y;
      red[t].z += red[t + st].z; red[t].w += red[t + st].w;
    }
    __syncthreads();
  }
  if (!t) { kn[r] = red[0].x; yb[r] = red[0].y; y1[r] = red[0].z; y0[r] = red[0].w; }
}

// ---------------- fused S-GEMM + dist + prior + log_softmax (recompute, no v traffic) ----------------
// Block (mt, b): 64 rows x 1024 cols.  512 threads = 8 waves (2 row-groups x 4 col-groups).
// Grid 32x16 = 512 blocks -> 2 blocks/CU, 16 waves/CU (2x the previous occupancy).
// Pass 0: compute v, online per-lane (m,s); shfl+LDS merge -> lsef[64].
// Pass 1: recompute v, subtract lse, stage 64x128 fp32 tile in LDS, store 512B row-segments.
#define L2E 1.4426950408889634f
__global__ __launch_bounds__(512) void smax_k(
    const u16* __restrict__ Wq, const u16* __restrict__ Z2, float* __restrict__ out,
    const float* __restrict__ ybv, const float* __restrict__ y1v, const float* __restrict__ y0v,
    const float* __restrict__ bqmv, const float* __restrict__ qc2_b,
    const float* __restrict__ qnv, const float* __restrict__ knv, const float* __restrict__ c1v,
    const float* __restrict__ crowv, const float* __restrict__ t12v,
    const int* __restrict__ qlens, const int* __restrict__ klens)
{
  __shared__ float vst[64][132];      // 33.8 KB store-staging
  __shared__ float t12s[1088];        // t12 slice: rl + gj in [0, 64+1024)
  __shared__ float qns[64], crs[64], bqms[64], q2bs[64];
  __shared__ float2 lseb[4][64];
  __shared__ float lsef[64];

  const int mt = blockIdx.x, b = blockIdx.y;
  const int m0 = mt * 64;
  const int t = threadIdx.x;
  const int w = t >> 6, lane = t & 63;
  const int wm2 = (w >> 2) * 32;      // 0 / 32
  const int wn2 = (w & 3) * 32;       // 0,32,64,96 (within each 128-col n-tile)
  const int fr = lane & 15, fk = (lane >> 4) << 3;
  const int fr4 = (lane >> 4) << 2, fc = lane & 15;
  const int qlv = qlens[b], klv = klens[b];

  if (t < 64) {
    qns[t]  = qnv[(long)b * TQ + m0 + t];
    crs[t]  = crowv[(long)b * TQ + m0 + t];
    bqms[t] = bqmv[m0 + t];
    q2bs[t] = qc2_b[m0 + t];
  }
  for (int k = t; k < 1088; k += 512) t12s[k] = t12v[(long)b * T12N + m0 + k];

  // A fragments in registers: Wq rows [m0+wm2, +32), K=128
  bf16x8 af[4][2];
#pragma unroll
  for (int kc = 0; kc < 4; kc++)
#pragma unroll
    for (int mi = 0; mi < 2; mi++)
      af[kc][mi] = *reinterpret_cast<const bf16x8*>(
          Wq + (long)(m0 + wm2 + mi * 16 + fr) * QDP + kc * 32 + fk);

  const u16* Zb = Z2 + (long)b * TK * QDP;
  const float* ybp = ybv + (long)b * TK;
  const float* y1p = y1v + (long)b * TK;
  const float* y0p = y0v + (long)b * TK;
  const float* knp = knv + (long)b * TK;
  const float* c1p = c1v + (long)b * TK;
  float* outp = out + (long)b * TQ * TK + (long)m0 * TK;

  float m_[8], s_[8];                 // 2 mi x 4 rr
#pragma unroll
  for (int ri = 0; ri < 8; ri++) { m_[ri] = -3.0e38f; s_[ri] = 0.f; }

  __syncthreads();

  for (int pass = 0; pass < 2; pass++) {
    for (int nt = 0; nt < 8; nt++) {
      // B fragments straight from L2-resident Z2
      bf16x8 bfr[4][2];
#pragma unroll
      for (int kc = 0; kc < 4; kc++)
#pragma unroll
        for (int nj = 0; nj < 2; nj++)
          bfr[kc][nj] = *reinterpret_cast<const bf16x8*>(
              Zb + (long)(nt * 128 + wn2 + nj * 16 + fr) * QDP + kc * 32 + fk);

      floatx4 acc[2][2];
#pragma unroll
      for (int mi = 0; mi < 2; mi++)
#pragma unroll
        for (int nj = 0; nj < 2; nj++) acc[mi][nj] = (floatx4){0.f, 0.f, 0.f, 0.f};
#pragma unroll
      for (int kc = 0; kc < 4; kc++)
#pragma unroll
        for (int mi = 0; mi < 2; mi++)
#pragma unroll
          for (int nj = 0; nj < 2; nj++)
            acc[mi][nj] = __builtin_amdgcn_mfma_f32_16x16x32_bf16(af[kc][mi], bfr[kc][nj], acc[mi][nj], 0, 0, 0);

      // j-side vectors for this lane's two columns
      int gj[2]; float ybj[2], y1j[2], y0j[2], knj[2], c1j[2];
#pragma unroll
      for (int nj = 0; nj < 2; nj++) {
        gj[nj]  = nt * 128 + wn2 + nj * 16 + fc;
        ybj[nj] = ybp[gj[nj]]; y1j[nj] = y1p[gj[nj]]; y0j[nj] = y0p[gj[nj]];
        knj[nj] = knp[gj[nj]]; c1j[nj] = c1p[gj[nj]];
      }

#pragma unroll
      for (int mi = 0; mi < 2; mi++) {
#pragma unroll
        for (int rr = 0; rr < 4; rr++) {
          const int rl = wm2 + mi * 16 + fr4 + rr;
          const float qnr = qns[rl], crr = crs[rl], bqr = bqms[rl], q2r = q2bs[rl];
          float vv[2];
#pragma unroll
          for (int nj = 0; nj < 2; nj++) {
            const float Sv = acc[mi][nj][rr] + ybj[nj] + bqr * y1j[nj] + q2r * y0j[nj];
            const float sq = fmaxf(qnr + knj[nj] - 2.0f * Sv, 1e-12f);
            const float x = -__builtin_amdgcn_sqrtf(sq) + crr - c1j[nj] + t12s[rl + gj[nj]];
            vv[nj] = ((m0 + rl) < qlv && gj[nj] < klv) ? x : -1e9f;
          }
          const int ri = mi * 4 + rr;
          if (pass == 0) {
            const float nm = fmaxf(m_[ri], fmaxf(vv[0], vv[1]));
            s_[ri] = s_[ri] * exp2f((m_[ri] - nm) * L2E)
                   + exp2f((vv[0] - nm) * L2E) + exp2f((vv[1] - nm) * L2E);
            m_[ri] = nm;
          } else {
            const float l = lsef[rl];
            acc[mi][0][rr] = vv[0] - l;
            acc[mi][1][rr] = vv[1] - l;
          }
        }
      }

      if (pass == 1) {
        // all 8 waves stage the 64x128 tile, then cooperative 512B-segment stores
#pragma unroll
        for (int mi = 0; mi < 2; mi++)
#pragma unroll
          for (int nj = 0; nj < 2; nj++)
#pragma unroll
            for (int rr = 0; rr < 4; rr++)
              vst[wm2 + mi * 16 + fr4 + rr][wn2 + nj * 16 + fc] = acc[mi][nj][rr];
        __syncthreads();
#pragma unroll
        for (int k = 0; k < 4; k++) {
          const int fi = k * 512 + t;
          const int row = fi >> 5, lc4 = (fi & 31) << 2;
          *reinterpret_cast<float4*>(outp + (long)row * TK + nt * 128 + lc4) =
              *reinterpret_cast<const float4*>(&vst[row][lc4]);
        }
        __syncthreads();
      }
    }

    if (pass == 0) {
      // merge (m,s) across the 16 fc lanes of each row
#pragma unroll
      for (int k2 = 1; k2 <= 8; k2 <<= 1) {
#pragma unroll
        for (int ri = 0; ri < 8; ri++) {
          const float om = __shfl_xor(m_[ri], k2, 64);
          const float os = __shfl_xor(s_[ri], k2, 64);
          const float nm = fmaxf(m_[ri], om);
          s_[ri] = s_[ri] * exp2f((m_[ri] - nm) * L2E) + os * exp2f((om - nm) * L2E);
          m_[ri] = nm;
        }
      }
      if (fc == 0) {
#pragma unroll
        for (int mi = 0; mi < 2; mi++)
#pragma unroll
          for (int rr = 0; rr < 4; rr++)
            lseb[w & 3][wm2 + mi * 16 + fr4 + rr] = make_float2(m_[mi * 4 + rr], s_[mi * 4 + rr]);
      }
      __syncthreads();
      if (t < 64) {
        const float2 e0 = lseb[0][t], e1 = lseb[1][t], e2 = lseb[2][t], e3 = lseb[3][t];
        const float mm = fmaxf(fmaxf(e0.x, e1.x), fmaxf(e2.x, e3.x));
        const float ss = e0.y * exp2f((e0.x - mm) * L2E) + e1.y * exp2f((e1.x - mm) * L2E)
                       + e2.y * exp2f((e2.x - mm) * L2E) + e3.y * exp2f((e3.x - mm) * L2E);
        lsef[t] = mm + logf(ss);
      }
      __syncthreads();
    }
  }
}

// ---------------- host ----------------
extern "C" void kernel_launch(void* const* d_in, const int* in_sizes, int n_in,
                              void* d_out, int out_size, void* d_ws, size_t ws_size,
                              hipStream_t stream)
{
  (void)in_sizes; (void)n_in; (void)out_size; (void)ws_size;
  const float* query = (const float*)d_in[0];
  const float* key   = (const float*)d_in[1];
  const int*   qlens = (const int*)d_in[2];
  const int*   klens = (const int*)d_in[3];
  const float* qc1_w = (const float*)d_in[4];
  const float* qc1_b = (const float*)d_in[5];
  const float* qc2_w = (const float*)d_in[6];
  const float* qc2_b = (const float*)d_in[7];
  const float* ql_w  = (const float*)d_in[8];
  const float* ql_b  = (const float*)d_in[9];
  const float* kc_w  = (const float*)d_in[10];
  const float* kc_b  = (const float*)d_in[11];
  const float* kl1_w = (const float*)d_in[12];
  const float* kl1_b = (const float*)d_in[13];
  const float* kl2_w = (const float*)d_in[14];
  const float* kl2_b = (const float*)d_in[15];

  size_t off = 0;
  char* ws = (char*)d_ws;
  auto alloc = [&](size_t bytes) -> char* {
    char* p = ws + off; off += (bytes + 255) & ~(size_t)255; return p;
  };
  // Front region (all dead by step 10): pool0 + qlw2 + kcp + TpT + pool = 69.2 MB
  u16* qc2w_bf = (u16*)alloc(2ull * H2 * H2);        //  8.39 MB
  u16* qc1T_bf = (u16*)alloc(2ull * QDP * H2);       //  0.52 MB
  u16* kl2w_bf = (u16*)alloc(2ull * HH * H2);        //  4.19 MB
  u16* kl1T_bf = (u16*)alloc(2ull * HH * H2);        //  4.19 MB
  u16* qT_bf   = (u16*)alloc(2ull * BB * QDP * 2048);//  8.39 MB   [pool0 = 25.69 MB]
  u16* kcolT_bf= (u16*)d_ws;                         // 25.17 MB overlay of pool0 (dead after X-GEMM)
  u16* Z2_bf   = (u16*)d_ws;                         //  4.19 MB overlay at front (written step 8)
  u16* qlw2_bf = (u16*)alloc(2ull * HH * 2048);      //  4.19 MB
  u16* kcp_bf  = (u16*)alloc(2ull * HH * 768);       //  1.57 MB
  u16* TpT_bf  = (u16*)alloc(2ull * H2 * HH);        //  4.19 MB  (rows = b*128+d, cols h)
  char* pool   = alloc(2ull * BB * HH * NKEY);       // 33.55 MB: split-K partials / X
  float* Pbuf  = (float*)pool;                       // fp32 partials (max 33.5 MB)
  u16* X_bf    = (u16*)pool;                         // X[b] (1024h x 768r) bf16, 25.2 MB
  // Region B: persistent through step 10
  float* tbl  = (float*)alloc(4ull * 8192);
  u16* Wq_bf  = (u16*)alloc(2ull * H2 * QDP);
  u16* Wk_bf  = (u16*)alloc(2ull * HH * NKEY);
  float* bqm  = (float*)alloc(4ull * H2);
  float* bkv  = (float*)alloc(4ull * HH);
  float* s1v  = (float*)alloc(4ull * HH);
  float* s0v  = (float*)alloc(4ull * HH);
  float* wsum = (float*)alloc(4ull * HH);
  float* colsum1 = (float*)alloc(4ull * H2);
  u16* K3_bf  = (u16*)alloc(2ull * BB * TK * HH);    // 33.55 MB
  float* qnv  = (float*)alloc(4ull * BB * TQ);
  float* knv  = (float*)alloc(4ull * BB * TK);
  float* ybv  = (float*)alloc(4ull * BB * TK);
  float* y1v  = (float*)alloc(4ull * BB * TK);
  float* y0v  = (float*)alloc(4ull * BB * TK);
  float* u0v  = (float*)alloc(4ull * BB * QDP);
  float* u1v  = (float*)alloc(4ull * BB * QDP);
  float* u2v  = (float*)alloc(4ull * BB * QDP);
  float* c1v  = (float*)alloc(4ull * BB * TK);
  float* crowv= (float*)alloc(4ull * BB * TQ);
  float* t12v = (float*)alloc(4ull * BB * T12N);
  float* scv  = (float*)alloc(256);
  // Parked in d_out (consumed by step 6, before step 10 overwrites d_out):
  float* WqG  = (float*)d_out;                              // 16.78 MB fp32
  u16* G_bf   = (u16*)((char*)d_out + 16777216);            //  0.52 MB

  // 1. prep (casts, qlw2, kcp, colsum, lgamma) + tiled transposes + bias folds
  prep_all_k<<<37920, 256, 0, stream>>>(qc2_w, kl2_w, ql_w, kc_w, kl1_w,
                                        qc2w_bf, kl2w_bf, qlw2_bf, kcp_bf, colsum1, tbl);
  tpack_k<<<1600, 256, 0, stream>>>(kl1_w, qc1_w, query, kl1T_bf, qc1T_bf, qT_bf);
  fold_bias_k<<<4096, 256, 0, stream>>>(qc2_w, qc1_b, qc2_b, kl2_w, kl1_b, kl2_b, ql_w, colsum1,
                                        bqm, bkv, s1v, s0v, wsum);

  // 2. Wq = qc2_w @ qc1_w-fold (2048x128), split-K 16 (KS=128)
  gemm_bt<1><<<dim3(1, 16, 16), 256, 0, stream>>>(qc2w_bf, qc1T_bf, Pbuf, H2, QDP, 128,
      H2, H2, 0, 16, 0, 0, (long)H2 * QDP, 0,
      nullptr, nullptr, nullptr, nullptr, nullptr, nullptr);
  reduce_bk_k<<<256, 256, 0, stream>>>(Pbuf, Wq_bf, (long)H2 * QDP, 16, (long)H2 * QDP);

  // 3. Wk = kl2_w @ kl1_w-fold (1024x1024), split-K 8 (KS=256)
  gemm_bt<1><<<dim3(8, 8, 8), 256, 0, stream>>>(kl2w_bf, kl1T_bf, Pbuf, HH, NKEY, 256,
      H2, H2, 0, 8, 0, 0, (long)HH * NKEY, 0,
      nullptr, nullptr, nullptr, nullptr, nullptr, nullptr);
  reduce_bk_k<<<1024, 256, 0, stream>>>(Pbuf, Wk_bf, (long)HH * NKEY, 8, (long)HH * NKEY);

  // 4. TpT (2048 x 1024) = qT @ qlw2^T, split-K 4 (KS=512)
  gemm_bt<1><<<dim3(8, 16, 4), 256, 0, stream>>>(qT_bf, qlw2_bf, Pbuf, H2, HH, 512,
      2048, 2048, 0, 4, 0, 0, (long)H2 * HH, 0,
      nullptr, nullptr, nullptr, nullptr, nullptr, nullptr);
  reduce_bk_k<<<2048, 256, 0, stream>>>(Pbuf, TpT_bf, (long)H2 * HH, 4, (long)H2 * HH);

  // 5. G[b] = TpT_b @ TpT_b^T (128x128 Gram per batch), split-K 8 (KS=128)
  gemm_bt<1><<<dim3(1, 1, 128), 256, 0, stream>>>(TpT_bf, TpT_bf, Pbuf, 128, 128, 128,
      HH, HH, 0, 8, (long)QDP * HH, (long)QDP * HH, 128 * 128, 0,
      nullptr, nullptr, nullptr, nullptr, nullptr, nullptr);
  reduce_bk_k<<<256, 256, 0, stream>>>(Pbuf, G_bf, 128 * 128, 8, (long)BB * 128 * 128);

  // 6. WqG[b] = Wq @ G[b]  (fp32, G symmetric) ; u-vectors + scalars + prior tables ; qn
  gemm_bt<1><<<dim3(1, 16, 16), 256, 0, stream>>>(Wq_bf, G_bf, WqG, H2, QDP, QDP,
      QDP, QDP, 0, 1, 0, (long)QDP * QDP, (long)H2 * QDP, 0,
      nullptr, nullptr, nullptr, nullptr, nullptr, nullptr);
  u_k<<<BB * QDP + 6 + 64 + 128 + 192, 256, 0, stream>>>(TpT_bf, ql_b, s1v, s0v, tbl, qlens, klens,
                                                         u0v, u1v, u2v, scv, c1v, crowv, t12v);
  qn_k<<<BB * TQ / 2, 256, 0, stream>>>(Wq_bf, WqG, u0v, u1v, u2v, bqm, qc2_b, scv, qnv);

  // 7. key branch, reassociated: X[b] = Wk @ kcolT[b]^T ; K3[b] = kcp @ X[b]^T + biases
  pack_kcolT_k<<<1024, 256, 0, stream>>>(key, kcolT_bf);
  gemm_bt<0><<<dim3(6, 8, BB), 256, 0, stream>>>(Wk_bf, kcolT_bf, X_bf, HH, 768, NKEY,
      NKEY, NKEY, 0, 1, 0, (long)768 * NKEY, (long)HH * 768, 0,
      nullptr, nullptr, nullptr, nullptr, nullptr, nullptr);
  gemm_bt<0><<<dim3(8, 8, BB), 256, 0, stream>>>(kcp_bf, X_bf, K3_bf, HH, NKEY, 768,
      768, 768, 1, 1, 0, (long)HH * 768, (long)TK * HH, 0,
      bkv, nullptr, kc_b, wsum, nullptr, nullptr);

  // 8. Z2[b] = K3[b] @ TpT_b^T (1024x128), split-K 2 (KS=512) -> Pbuf -> bf16 at d_ws front
  gemm_bt<1><<<dim3(8, 1, 32), 256, 0, stream>>>(K3_bf, TpT_bf, Pbuf, TK, QDP, 512,
      HH, HH, 1, 2, (long)TK * HH, (long)QDP * HH, (long)TK * QDP, 0,
      nullptr, nullptr, nullptr, nullptr, nullptr, nullptr);
  reduce_bk_k<<<2048, 256, 0, stream>>>(Pbuf, Z2_bf, (long)TK * QDP, 2, (long)BB * TK * QDP);

  // 9. K3 row norms + per-row bias dots (yb, y1, y0)
  rownormk_k<<<BB * TK, 256, 0, stream>>>(K3_bf, ql_b, s1v, s0v, knv, ybv, y1v, y0v);

  // 10. fused S-GEMM + dist + prior + log_softmax -> d_out (fp32), no intermediate
  smax_k<<<dim3(32, 16), 512, 0, stream>>>(Wq_bf, Z2_bf, (float*)d_out,
      ybv, y1v, y0v, bqm, qc2_b, qnv, knv, c1v, crowv, t12v, qlens, klens);
}

// Round 6
// 616.886 us; speedup vs baseline: 1.0283x; 1.0283x over previous
//
#include <hip/hip_runtime.h>
#include <math.h>

typedef unsigned short u16;
typedef float floatx4 __attribute__((ext_vector_type(4)));
typedef __bf16 bf16x8 __attribute__((ext_vector_type(8)));

// Problem constants
#define BB   16
#define TQ   2048   // query length after convs (= 2H)
#define TK   1024   // key rows (= H)
#define HH   1024   // H
#define H2   2048   // 2H
#define QD   80
#define QDP  128    // QD padded to tile width (zero-filled)
#define KD   256
#define NQ   2044
#define NKEY 1024
#define T12N 3072   // t12 table stride per batch (covers s = i+j in [0, 3071))

__device__ __forceinline__ u16 f2bf(float f) {
  unsigned int u = __float_as_uint(f);
  u = u + 0x7fffu + ((u >> 16) & 1u);
  return (u16)(u >> 16);
}
__device__ __forceinline__ float bf2f(u16 s) {
  return __uint_as_float(((unsigned int)s) << 16);
}
__device__ __forceinline__ float tgf(const float* __restrict__ tbl, int x) {
  return tbl[(x < 8191) ? (x < 0 ? 0 : x) : 8191];
}

// ---------------- fused prep: elementwise packs + kl1 row-sums + lgamma table ----------------
// segments (blocks): qc2w 16384 | kl2w 8192 | qlw2 8192 | kcp 3072 | colsum 2048 | lgamma 32
//   => grid 37920
__global__ __launch_bounds__(256) void prep_all_k(
    const float* __restrict__ qc2_w, const float* __restrict__ kl2_w,
    const float* __restrict__ ql_w, const float* __restrict__ kc_w,
    const float* __restrict__ kl1_w,
    u16* __restrict__ qc2w, u16* __restrict__ kl2w, u16* __restrict__ qlw2,
    u16* __restrict__ kcp, float* __restrict__ colsum1, float* __restrict__ tbl)
{
  long b = blockIdx.x;
  const int t = threadIdx.x;
  __shared__ float red[256];
  if (b < 16384) {                       // qc2w: cast (2048x2048)
    long i = b * 256 + t; qc2w[i] = f2bf(qc2_w[i]); return;
  }
  b -= 16384;
  if (b < 8192) {                        // kl2w: cast (1024x2048)
    long i = b * 256 + t; kl2w[i] = f2bf(kl2_w[i]); return;
  }
  b -= 8192;
  if (b < 8192) {                        // qlw2[h,n] = ql_w[h,n+2], n<2044 else 0
    long i = b * 256 + t;
    int n = (int)(i & 2047);
    int h = (int)(i >> 11);
    qlw2[i] = (n < NQ) ? f2bf(ql_w[(long)h * H2 + n + 2]) : (u16)0; return;
  }
  b -= 8192;
  if (b < 3072) {                        // kcp: (1024,256,3)->(1024,768), kk=t*256+d
    long i = b * 256 + t;
    int r = (int)(i % 768);
    int o = (int)(i / 768);
    int tt = r >> 8, d = r & 255;
    kcp[i] = f2bf(kc_w[((long)o * KD + d) * 3 + tt]); return;
  }
  b -= 3072;
  if (b < 2048) {                        // colsum1[o] = sum_n kl1_w[o,n]
    const float* row = kl1_w + b * (long)HH;
    float s = row[t] + row[t + 256] + row[t + 512] + row[t + 768];
    red[t] = s; __syncthreads();
    for (int st = 128; st > 0; st >>= 1) { if (t < st) red[t] += red[t + st]; __syncthreads(); }
    if (!t) colsum1[b] = red[0];
    return;
  }
  b -= 2048;
  { int i = (int)(b * 256 + t); if (i < 8192) tbl[i] = i ? (float)lgamma((double)i) : 0.0f; }
}

// ---------------- tiled transposes (fp32 src -> bf16 dst), 64x64 LDS tiles ----------------
// segments: kl1T 512 | qc1T 64 | qT 1024  => grid 1600
__global__ __launch_bounds__(256) void tpack_k(
    const float* __restrict__ kl1_w, const float* __restrict__ qc1_w,
    const float* __restrict__ query,
    u16* __restrict__ kl1T, u16* __restrict__ qc1T, u16* __restrict__ qT)
{
  __shared__ float tile[64][65];
  int bid = blockIdx.x;
  const int tid = threadIdx.x;
  const int r4 = tid >> 6, c = tid & 63;
  const float* src; u16* dst;
  int sr0, sc0, srcR, srcC, srcStride, dstC;
  if (bid < 512) {                       // kl1T: (2048x1024) -> (1024x2048)
    sr0 = (bid >> 4) * 64; sc0 = (bid & 15) * 64;
    src = kl1_w; srcR = 2048; srcC = 1024; srcStride = 1024;
    dst = kl1T; dstC = 2048;
  } else if ((bid -= 512) < 64) {        // qc1T: (2048x80) -> (128x2048)
    sr0 = (bid >> 1) * 64; sc0 = (bid & 1) * 64;
    src = qc1_w; srcR = 2048; srcC = QD; srcStride = QD;
    dst = qc1T; dstC = 2048;
  } else {                               // qT: per b, (2044x80) -> (128x2048)
    bid -= 64;
    const int b16 = bid >> 6, r = bid & 63;
    sr0 = (r >> 1) * 64; sc0 = (r & 1) * 64;
    src = query + (long)b16 * NQ * QD; srcR = NQ; srcC = QD; srcStride = QD;
    dst = qT + (long)b16 * QDP * 2048; dstC = 2048;
  }
#pragma unroll
  for (int rr = r4; rr < 64; rr += 4) {
    const int gr = sr0 + rr, gc = sc0 + c;
    tile[rr][c] = (gr < srcR && gc < srcC) ? src[(long)gr * srcStride + gc] : 0.f;
  }
  __syncthreads();
#pragma unroll
  for (int rr = r4; rr < 64; rr += 4)
    dst[(long)(sc0 + rr) * dstC + sr0 + c] = f2bf(tile[c][rr]);
}

// ---------------- transposed im2col: kcolT[b][(t,d)][n] = key[b, n+t-1, d] ----------------
// grid 1024: b = bid>>6; tile (m0,d0) of key[b]; writes 3 shifted transposed tiles.
__global__ __launch_bounds__(256) void pack_kcolT_k(const float* __restrict__ key, u16* __restrict__ out) {
  __shared__ float tile[64][65];
  const int bid = blockIdx.x, tid = threadIdx.x;
  const int b = bid >> 6, r = bid & 63;
  const int m0 = (r >> 2) * 64;          // key row (position) tile
  const int d0 = (r & 3) * 64;           // key col (channel) tile
  const int r4 = tid >> 6, c = tid & 63;
#pragma unroll
  for (int rr = r4; rr < 64; rr += 4)
    tile[rr][c] = key[((long)b * NKEY + m0 + rr) * KD + d0 + c];
  __syncthreads();
#pragma unroll
  for (int t = 0; t < 3; t++) {
    const int n = m0 + 1 - t + c;
    if (n >= 0 && n < NKEY) {
#pragma unroll
      for (int rr = r4; rr < 64; rr += 4)
        out[((long)b * 768 + t * 256 + d0 + rr) * NKEY + n] = f2bf(tile[c][rr]);
    }
  }
  // zero the never-written boundary columns: (t=0, n=0) and (t=2, n=1023)
  if (m0 == 0 && c == 0) {
#pragma unroll
    for (int rr = r4; rr < 64; rr += 4)
      out[((long)b * 768 + d0 + rr) * NKEY + 0] = (u16)0;
  }
  if (m0 == 960 && c == 0) {
#pragma unroll
    for (int rr = r4; rr < 64; rr += 4)
      out[((long)b * 768 + 512 + d0 + rr) * NKEY + (NKEY - 1)] = (u16)0;
  }
}

// ---------------- fused bias folds (+ wsum) ----------------
// grid = H2 (bqm) + HH (bkv+wsum) + HH (s1/s0) = 4096
__global__ __launch_bounds__(256) void fold_bias_k(
    const float* __restrict__ qc2_w, const float* __restrict__ qc1_b, const float* __restrict__ qc2_b,
    const float* __restrict__ kl2_w, const float* __restrict__ kl1_b, const float* __restrict__ kl2_b,
    const float* __restrict__ ql_w, const float* __restrict__ colsum1,
    float* __restrict__ bqm, float* __restrict__ bkv, float* __restrict__ s1v, float* __restrict__ s0v,
    float* __restrict__ wsum)
{
  const int bid = blockIdx.x, t = threadIdx.x;
  float s = 0.f, s2 = 0.f;
  if (bid < H2) {
    const float* row = qc2_w + (long)bid * H2;
    for (int k = t; k < H2; k += 256) s += row[k] * qc1_b[k];
  } else if (bid < H2 + HH) {
    const float* row = kl2_w + (long)(bid - H2) * H2;
    for (int k = t; k < H2; k += 256) { const float rv = row[k]; s += rv * kl1_b[k]; s2 += rv * colsum1[k]; }
  } else {
    const float* row = ql_w + (long)(bid - H2 - HH) * H2;
    for (int m = 1 + t; m <= H2 - 2; m += 256) s += row[m];
  }
  __shared__ float red[256];
  __shared__ float red2[256];
  red[t] = s; red2[t] = s2; __syncthreads();
  for (int st = 128; st > 0; st >>= 1) {
    if (t < st) { red[t] += red[t + st]; red2[t] += red2[t + st]; }
    __syncthreads();
  }
  if (!t) {
    if (bid < H2) bqm[bid] = red[0] + qc2_b[bid];
    else if (bid < H2 + HH) { bkv[bid - H2] = red[0] + kl2_b[bid - H2]; wsum[bid - H2] = red2[0]; }
    else {
      int h = bid - H2 - HH;
      s1v[h] = red[0];
      s0v[h] = ql_w[(long)h * H2] + ql_w[(long)h * H2 + H2 - 1];
    }
  }
}

// ---------------- MFMA GEMM: C[b] = A[b] @ B[b]^T (+ biases) ----------------
// Requires: M%128==0, N%128==0, K%32==0, lda/ldb%8==0, 16B-aligned bases.
// kspl: blockIdx.z decodes as (batch = z/kspl, kslice = z%kspl).
// OUTF32 = 1: write fp32 raw; OUTF32 = 0: bf16 with epilogue
//   + colb[n] + rowb[m] + r1m[m]*r1n[n] + r2m[m]*r2n[n]  (null = skip);
//   colb/r1n/r2n advance by batch*sN (per-batch n-side vectors).
__device__ __forceinline__ void gld_lds16(const u16* g, u16* l) {
  __builtin_amdgcn_global_load_lds((const __attribute__((address_space(1))) void*)g,
                                   (__attribute__((address_space(3))) void*)l, 16, 0, 0);
}

template<int OUTF32>
__global__ __launch_bounds__(256) void gemm_bt(
    const u16* __restrict__ A, const u16* __restrict__ B, void* __restrict__ Cv,
    int M, int N, int K, int lda, int ldb, int swap, int kspl,
    long sA, long sB, long sC, long sN,
    const float* __restrict__ colb, const float* __restrict__ rowb,
    const float* __restrict__ r1m, const float* __restrict__ r1n,
    const float* __restrict__ r2m, const float* __restrict__ r2n)
{
  __shared__ __align__(16) u16 As[128 * 32];   // 8 KB
  __shared__ __align__(16) u16 Bs[128 * 32];   // 8 KB
  const int bz = blockIdx.z;
  const int bb_ = (kspl > 1) ? bz / kspl : bz;
  const int ks_ = (kspl > 1) ? bz - bb_ * kspl : 0;
  const int tid  = threadIdx.x;
  const int lane = tid & 63;
  const int wv = tid >> 6;                // wave 0..3
  const int wm = ((tid >> 7) & 1) * 64;   // wave row offset
  const int wn = ((tid >> 6) & 1) * 64;   // wave col offset
  const int m0 = (swap ? blockIdx.x : blockIdx.y) * 128;
  const int n0 = (swap ? blockIdx.y : blockIdx.x) * 128;

  // staging: wave wv covers rows [wv*32, wv*32+32) of both tiles, 2 instrs of 16 rows each
  const int srow = wv * 32 + (lane >> 2);       // lane's source row within tile (first instr)
  const int scol = (lane & 3) << 3;             // 0,8,16,24
  const u16* ga = A + bb_ * sA + (long)ks_ * K + (long)(m0 + srow) * lda + scol;
  const u16* gb = B + bb_ * sB + (long)ks_ * K + (long)(n0 + srow) * ldb + scol;
  u16* la0 = &As[(wv * 32) * 32];
  u16* la1 = &As[(wv * 32 + 16) * 32];
  u16* lb0 = &Bs[(wv * 32) * 32];
  u16* lb1 = &Bs[(wv * 32 + 16) * 32];
  const long a16 = (long)16 * lda;
  const long b16 = (long)16 * ldb;

  floatx4 acc[4][4];
#pragma unroll
  for (int a_ = 0; a_ < 4; a_++)
#pragma unroll
    for (int b_ = 0; b_ < 4; b_++) acc[a_][b_] = (floatx4){0.f, 0.f, 0.f, 0.f};

  const int fr = lane & 15;         // frag row/col within 16
  const int fk = (lane >> 4) << 3;  // frag k offset

  for (int kb = 0; kb < K; kb += 32) {
    gld_lds16(ga,       la0);
    gld_lds16(ga + a16, la1);
    gld_lds16(gb,       lb0);
    gld_lds16(gb + b16, lb1);
    ga += 32; gb += 32;
    __syncthreads();
    bf16x8 af[4], bfr[4];
#pragma unroll
    for (int mi = 0; mi < 4; mi++)
      af[mi] = *reinterpret_cast<const bf16x8*>(&As[(wm + mi * 16 + fr) * 32 + fk]);
#pragma unroll
    for (int ni = 0; ni < 4; ni++)
      bfr[ni] = *reinterpret_cast<const bf16x8*>(&Bs[(wn + ni * 16 + fr) * 32 + fk]);
#pragma unroll
    for (int mi = 0; mi < 4; mi++)
#pragma unroll
      for (int ni = 0; ni < 4; ni++)
        acc[mi][ni] = __builtin_amdgcn_mfma_f32_16x16x32_bf16(af[mi], bfr[ni], acc[mi][ni], 0, 0, 0);
    __syncthreads();
  }

  // epilogue: C/D layout col=lane&15, row=(lane>>4)*4+reg  [m89-verified]
  const int fr4 = (lane >> 4) << 2;
  const int fc  = lane & 15;
  u16*   Cb16 = (u16*)Cv + (long)bz * sC;
  float* Cb32 = (float*)Cv + (long)bz * sC;
  const float* cbp  = colb ? colb + (long)bb_ * sN : nullptr;
  const float* r1np = r1n ? r1n + (long)bb_ * sN : nullptr;
  const float* r2np = r2n ? r2n + (long)bb_ * sN : nullptr;
#pragma unroll
  for (int mi = 0; mi < 4; mi++) {
#pragma unroll
    for (int ni = 0; ni < 4; ni++) {
      const int gm0 = m0 + wm + mi * 16 + fr4;
      const int gn  = n0 + wn + ni * 16 + fc;
      const float cbv  = cbp ? cbp[gn] : 0.f;
      const float r1nv = r1np ? r1np[gn] : 0.f;
      const float r2nv = r2np ? r2np[gn] : 0.f;
#pragma unroll
      for (int rr = 0; rr < 4; rr++) {
        const int gm = gm0 + rr;
        float v = acc[mi][ni][rr] + cbv;
        if (rowb) v += rowb[gm];
        if (r1m)  v += r1m[gm] * r1nv;
        if (r2m)  v += r2m[gm] * r2nv;
        if (OUTF32) Cb32[(long)gm * N + gn] = v;
        else        Cb16[(long)gm * N + gn] = f2bf(v);
      }
    }
  }
}

// ---------------- split-K reduce (batch-major planes) ----------------
__global__ __launch_bounds__(256) void reduce_bk_k(const float* __restrict__ P, u16* __restrict__ out,
                                                   long chunk, int S, long total) {
  long j = ((long)blockIdx.x * 256 + threadIdx.x) * 4;
  if (j >= total) return;
  long b = j / chunk;
  const float* p = P + j + b * chunk * (S - 1);
  float4 s = *reinterpret_cast<const float4*>(p);
  for (int t = 1; t < S; t++) {
    const float4 v = *reinterpret_cast<const float4*>(p + (long)t * chunk);
    s.x += v.x; s.y += v.y; s.z += v.z; s.w += v.w;
  }
  union { u16 h[4]; uint2 u; } o;
  o.h[0] = f2bf(s.x); o.h[1] = f2bf(s.y); o.h[2] = f2bf(s.z); o.h[3] = f2bf(s.w);
  *reinterpret_cast<uint2*>(out + j) = o.u;
}

// ---------------- u-vectors + bias-cross scalars + prior tables ----------------
// blocks 0..2047:      u{0,1,2}[b*128+d] = sum_h TpT[b*128+d, h] * {ql_b, s1v, s0v}[h]
// blocks 2048..2053:   sc[idx] pair dots
// blocks 2054..2117:   c1[b][j]  = lg(j+1) + lg(n_-j+1)
// blocks 2118..2245:   crow[b][i] = lg(n_+1)+lg(i+1+bb)-lg(i+1)-lg(bb)-lg(i+1+n_+bb)
// blocks 2246..2437:   t12[b][s] = lg(s+1) + lg(n_+ql-s)        (s = i+j)
__global__ __launch_bounds__(256) void u_k(
    const u16* __restrict__ TpT, const float* __restrict__ qlb,
    const float* __restrict__ s1, const float* __restrict__ s0,
    const float* __restrict__ tbl, const int* __restrict__ qlens, const int* __restrict__ klens,
    float* __restrict__ u0, float* __restrict__ u1, float* __restrict__ u2,
    float* __restrict__ sc, float* __restrict__ c1,
    float* __restrict__ crow, float* __restrict__ t12)
{
  const int bid = blockIdx.x, t = threadIdx.x;
  __shared__ float4 red[256];
  if (bid < BB * QDP) {
    uint2 v = reinterpret_cast<const uint2*>(TpT + (long)bid * HH)[t];
    float a0 = bf2f((u16)(v.x & 0xffff)), a1 = bf2f((u16)(v.x >> 16));
    float a2 = bf2f((u16)(v.y & 0xffff)), a3 = bf2f((u16)(v.y >> 16));
    float4 q  = reinterpret_cast<const float4*>(qlb)[t];
    float4 w1 = reinterpret_cast<const float4*>(s1)[t];
    float4 w0 = reinterpret_cast<const float4*>(s0)[t];
    float4 s;
    s.x = a0 * q.x  + a1 * q.y  + a2 * q.z  + a3 * q.w;
    s.y = a0 * w1.x + a1 * w1.y + a2 * w1.z + a3 * w1.w;
    s.z = a0 * w0.x + a1 * w0.y + a2 * w0.z + a3 * w0.w;
    s.w = 0.f;
    red[t] = s; __syncthreads();
    for (int st = 128; st > 0; st >>= 1) {
      if (t < st) { red[t].x += red[t + st].x; red[t].y += red[t + st].y; red[t].z += red[t + st].z; }
      __syncthreads();
    }
    if (!t) { u0[bid] = red[0].x; u1[bid] = red[0].y; u2[bid] = red[0].z; }
  } else if (bid < BB * QDP + 6) {
    const int idx = bid - BB * QDP;
    const float* X = (idx == 1 || idx == 5) ? s1 : (idx == 2) ? s0 : qlb;
    const float* Y = (idx == 1 || idx == 3) ? s1 : (idx == 0) ? qlb : s0;
    float4 x = reinterpret_cast<const float4*>(X)[t];
    float4 y = reinterpret_cast<const float4*>(Y)[t];
    float4 s; s.x = x.x * y.x + x.y * y.y + x.z * y.z + x.w * y.w; s.y = s.z = s.w = 0.f;
    red[t] = s; __syncthreads();
    for (int st = 128; st > 0; st >>= 1) {
      if (t < st) red[t].x += red[t + st].x;
      __syncthreads();
    }
    if (!t) sc[idx] = red[0].x;
  } else if (bid < BB * QDP + 6 + 64) {
    const int idx = bid - (BB * QDP + 6);
    const int b = idx >> 2;
    const int j = ((idx & 3) << 8) | t;
    const int kl = klens[b];
    const int n_ = (kl - 1 > 0) ? kl - 1 : 0;
    c1[b * TK + j] = tgf(tbl, j + 1) + tgf(tbl, n_ - j + 1);
  } else if (bid < BB * QDP + 6 + 64 + 128) {
    const int idx = bid - (BB * QDP + 6 + 64);
    const int b = idx >> 3;
    const int i = ((idx & 7) << 8) | t;
    const int ql = qlens[b], kl = klens[b];
    const int n_ = (kl - 1 > 0) ? kl - 1 : 0;
    const int bb = (ql - i > 1) ? ql - i : 1;
    crow[b * TQ + i] = tgf(tbl, n_ + 1) + tgf(tbl, i + 1 + bb) - tgf(tbl, i + 1)
                     - tgf(tbl, bb) - tgf(tbl, i + 1 + n_ + bb);
  } else {
    const int idx = bid - (BB * QDP + 6 + 64 + 128);
    const int b = idx / 12;
    const int s = (idx - b * 12) * 256 + t;
    const int ql = qlens[b], kl = klens[b];
    const int n_ = (kl - 1 > 0) ? kl - 1 : 0;
    t12[b * T12N + s] = tgf(tbl, s + 1) + tgf(tbl, n_ + ql - s);
  }
}

// ---------------- qn via Gram quadratic form ----------------
__global__ __launch_bounds__(256) void qn_k(
    const u16* __restrict__ Wq, const float* __restrict__ WqG,
    const float* __restrict__ u0, const float* __restrict__ u1, const float* __restrict__ u2,
    const float* __restrict__ bqm, const float* __restrict__ qc2_b,
    const float* __restrict__ sc, float* __restrict__ qn)
{
  const int bx = blockIdx.x, t = threadIdx.x;
  const int b = bx >> 10;
  const int i = ((bx & 1023) << 1) | (t >> 7);
  const int d = t & 127;
  const float w  = bf2f(Wq[(long)i * QDP + d]);
  const float g  = WqG[((long)b * H2 + i) * QDP + d];
  const float bq = bqm[i], q2 = qc2_b[i];
  const float uu = u0[b * QDP + d] + bq * u1[b * QDP + d] + q2 * u2[b * QDP + d];
  __shared__ float red[256];
  red[t] = w * (g + 2.f * uu); __syncthreads();
  for (int s = 64; s > 0; s >>= 1) { if ((t & 127) < s) red[t] += red[t + s]; __syncthreads(); }
  if (d == 0) {
    const float cst = sc[0] + bq * bq * sc[1] + q2 * q2 * sc[2]
                    + 2.f * (bq * sc[3] + q2 * sc[4] + bq * q2 * sc[5]);
    qn[b * TQ + i] = red[t] + cst;
  }
}

// ---------------- K3 row norms + the three per-row bias dots ----------------
__global__ __launch_bounds__(256) void rownormk_k(
    const u16* __restrict__ K3, const float* __restrict__ qlb,
    const float* __restrict__ s1, const float* __restrict__ s0,
    float* __restrict__ kn, float* __restrict__ yb, float* __restrict__ y1, float* __restrict__ y0)
{
  const long r = blockIdx.x;
  const int t = threadIdx.x;
  uint2 v = reinterpret_cast<const uint2*>(K3 + r * HH)[t];
  float a0 = bf2f((u16)(v.x & 0xffff)), a1 = bf2f((u16)(v.x >> 16));
  float a2 = bf2f((u16)(v.y & 0xffff)), a3 = bf2f((u16)(v.y >> 16));
  float4 q  = reinterpret_cast<const float4*>(qlb)[t];
  float4 w1 = reinterpret_cast<const float4*>(s1)[t];
  float4 w0 = reinterpret_cast<const float4*>(s0)[t];
  float4 s;
  s.x = a0 * a0   + a1 * a1   + a2 * a2   + a3 * a3;
  s.y = a0 * q.x  + a1 * q.y  + a2 * q.z  + a3 * q.w;
  s.z = a0 * w1.x + a1 * w1.y + a2 * w1.z + a3 * w1.w;
  s.w = a0 * w0.x + a1 * w0.y + a2 * w0.z + a3 * w0.w;
  __shared__ float4 red[256];
  red[t] = s; __syncthreads();
  for (int st = 128; st > 0; st >>= 1) {
    if (t < st) {
      red[t].x += red[t + st].x; red[t].y += red[t + st].y;
      red[t].z += red[t + st].z; red[t].w += red[t + st].w;
    }
    __syncthreads();
  }
  if (!t) { kn[r] = red[0].x; yb[r] = red[0].y; y1[r] = red[0].z; y0[r] = red[0].w; }
}

// ---------------- fused S-GEMM + dist + prior + log_softmax (recompute, no v traffic) ----------------
// Block (mt, b): 128 rows x 1024 cols.  1024 threads = 16 waves (4m x 4n) -> 16 waves/CU
// guaranteed resident (grid 16x16 = 1 block/CU; launch_bounds forces <=128 VGPR).
// No per-nt barriers: pass 0 computes v + online per-lane (m,s) (no stores); one merge;
// pass 1 recomputes v and stores directly from acc (64B segments; L2 assembles full lines).
// j-side vectors pre-combined in LDS: jA = kn-2*yb, jB = -2*y1, jC = -2*y0, jc1 = c1.
#define L2E 1.4426950408889634f
__global__ __launch_bounds__(1024) void smax_k(
    const u16* __restrict__ Wq, const u16* __restrict__ Z2, float* __restrict__ out,
    const float* __restrict__ ybv, const float* __restrict__ y1v, const float* __restrict__ y0v,
    const float* __restrict__ bqmv, const float* __restrict__ qc2_b,
    const float* __restrict__ qnv, const float* __restrict__ knv, const float* __restrict__ c1v,
    const float* __restrict__ crowv, const float* __restrict__ t12v,
    const int* __restrict__ qlens, const int* __restrict__ klens)
{
  __shared__ float t12s[1152];
  __shared__ float jA[1024], jB[1024], jC[1024], jc1[1024];
  __shared__ float qns[128], crs[128], bqms[128], q2bs[128];
  __shared__ float2 lseb[4][128];
  __shared__ float lsef[128];

  const int mt = blockIdx.x, b = blockIdx.y;
  const int m0 = mt * 128;
  const int t = threadIdx.x;
  const int w = t >> 6, lane = t & 63;
  const int wm2 = (w >> 2) * 32;      // 0,32,64,96
  const int wn2 = (w & 3) * 32;       // 0,32,64,96 (within each 128-col n-tile)
  const int fr = lane & 15, fk = (lane >> 4) << 3;
  const int fr4 = (lane >> 4) << 2, fc = lane & 15;
  const int qlv = qlens[b], klv = klens[b];

  if (t < 128) {
    qns[t]  = qnv[(long)b * TQ + m0 + t];
    crs[t]  = crowv[(long)b * TQ + m0 + t];
    bqms[t] = bqmv[m0 + t];
    q2bs[t] = qc2_b[m0 + t];
  }
  for (int k = t; k < 1152; k += 1024) t12s[k] = t12v[(long)b * T12N + m0 + k];
  {
    const int j = t;   // 1024 threads <-> 1024 columns
    const float kn = knv[(long)b * TK + j];
    const float yb = ybv[(long)b * TK + j];
    const float y1 = y1v[(long)b * TK + j];
    const float y0 = y0v[(long)b * TK + j];
    jA[j]  = kn - 2.f * yb;
    jB[j]  = -2.f * y1;
    jC[j]  = -2.f * y0;
    jc1[j] = c1v[(long)b * TK + j];
  }

  // A fragments in registers: Wq rows [m0+wm2, +32), K=128
  bf16x8 af[4][2];
#pragma unroll
  for (int kc = 0; kc < 4; kc++)
#pragma unroll
    for (int mi = 0; mi < 2; mi++)
      af[kc][mi] = *reinterpret_cast<const bf16x8*>(
          Wq + (long)(m0 + wm2 + mi * 16 + fr) * QDP + kc * 32 + fk);

  const u16* Zb = Z2 + (long)b * TK * QDP;
  float* outp = out + (long)b * TQ * TK + (long)m0 * TK;

  float m_[8], s_[8];                 // 2 mi x 4 rr
#pragma unroll
  for (int ri = 0; ri < 8; ri++) { m_[ri] = -3.0e38f; s_[ri] = 0.f; }

  __syncthreads();

  // -------- pass 0: online (m, s), no stores, no barriers --------
  for (int nt = 0; nt < 8; nt++) {
    bf16x8 bfr[4][2];
#pragma unroll
    for (int kc = 0; kc < 4; kc++)
#pragma unroll
      for (int nj = 0; nj < 2; nj++)
        bfr[kc][nj] = *reinterpret_cast<const bf16x8*>(
            Zb + (long)(nt * 128 + wn2 + nj * 16 + fr) * QDP + kc * 32 + fk);

    floatx4 acc[2][2];
#pragma unroll
    for (int mi = 0; mi < 2; mi++)
#pragma unroll
      for (int nj = 0; nj < 2; nj++) acc[mi][nj] = (floatx4){0.f, 0.f, 0.f, 0.f};
#pragma unroll
    for (int kc = 0; kc < 4; kc++)
#pragma unroll
      for (int mi = 0; mi < 2; mi++)
#pragma unroll
        for (int nj = 0; nj < 2; nj++)
          acc[mi][nj] = __builtin_amdgcn_mfma_f32_16x16x32_bf16(af[kc][mi], bfr[kc][nj], acc[mi][nj], 0, 0, 0);

    int gj[2]; float Aj[2], Bj[2], Cj[2], Dj[2];
#pragma unroll
    for (int nj = 0; nj < 2; nj++) {
      gj[nj] = nt * 128 + wn2 + nj * 16 + fc;
      Aj[nj] = jA[gj[nj]]; Bj[nj] = jB[gj[nj]]; Cj[nj] = jC[gj[nj]]; Dj[nj] = jc1[gj[nj]];
    }

#pragma unroll
    for (int mi = 0; mi < 2; mi++) {
#pragma unroll
      for (int rr = 0; rr < 4; rr++) {
        const int rl = wm2 + mi * 16 + fr4 + rr;
        const float qnr = qns[rl], crr = crs[rl], bqr = bqms[rl], q2r = q2bs[rl];
        float vv[2];
#pragma unroll
        for (int nj = 0; nj < 2; nj++) {
          const float sq = fmaxf(qnr + Aj[nj] + bqr * Bj[nj] + q2r * Cj[nj]
                                 - 2.0f * acc[mi][nj][rr], 1e-12f);
          const float x = -__builtin_amdgcn_sqrtf(sq) + crr - Dj[nj] + t12s[rl + gj[nj]];
          vv[nj] = ((m0 + rl) < qlv && gj[nj] < klv) ? x : -1e9f;
        }
        const int ri = mi * 4 + rr;
        const float nm = fmaxf(m_[ri], fmaxf(vv[0], vv[1]));
        s_[ri] = s_[ri] * exp2f((m_[ri] - nm) * L2E)
               + exp2f((vv[0] - nm) * L2E) + exp2f((vv[1] - nm) * L2E);
        m_[ri] = nm;
      }
    }
  }

  // -------- lse merge: shfl over fc lanes, LDS over the 4 n-group waves --------
#pragma unroll
  for (int k2 = 1; k2 <= 8; k2 <<= 1) {
#pragma unroll
    for (int ri = 0; ri < 8; ri++) {
      const float om = __shfl_xor(m_[ri], k2, 64);
      const float os = __shfl_xor(s_[ri], k2, 64);
      const float nm = fmaxf(m_[ri], om);
      s_[ri] = s_[ri] * exp2f((m_[ri] - nm) * L2E) + os * exp2f((om - nm) * L2E);
      m_[ri] = nm;
    }
  }
  if (fc == 0) {
#pragma unroll
    for (int mi = 0; mi < 2; mi++)
#pragma unroll
      for (int rr = 0; rr < 4; rr++)
        lseb[w & 3][wm2 + mi * 16 + fr4 + rr] = make_float2(m_[mi * 4 + rr], s_[mi * 4 + rr]);
  }
  __syncthreads();
  if (t < 128) {
    const float2 e0 = lseb[0][t], e1 = lseb[1][t], e2 = lseb[2][t], e3 = lseb[3][t];
    const float mm = fmaxf(fmaxf(e0.x, e1.x), fmaxf(e2.x, e3.x));
    const float ss = e0.y * exp2f((e0.x - mm) * L2E) + e1.y * exp2f((e1.x - mm) * L2E)
                   + e2.y * exp2f((e2.x - mm) * L2E) + e3.y * exp2f((e3.x - mm) * L2E);
    lsef[t] = mm + logf(ss);
  }
  __syncthreads();

  float lse_r[8];
#pragma unroll
  for (int mi = 0; mi < 2; mi++)
#pragma unroll
    for (int rr = 0; rr < 4; rr++)
      lse_r[mi * 4 + rr] = lsef[wm2 + mi * 16 + fr4 + rr];

  // -------- pass 1: recompute v, subtract lse, direct stores, no barriers --------
  for (int nt = 0; nt < 8; nt++) {
    bf16x8 bfr[4][2];
#pragma unroll
    for (int kc = 0; kc < 4; kc++)
#pragma unroll
      for (int nj = 0; nj < 2; nj++)
        bfr[kc][nj] = *reinterpret_cast<const bf16x8*>(
            Zb + (long)(nt * 128 + wn2 + nj * 16 + fr) * QDP + kc * 32 + fk);

    floatx4 acc[2][2];
#pragma unroll
    for (int mi = 0; mi < 2; mi++)
#pragma unroll
      for (int nj = 0; nj < 2; nj++) acc[mi][nj] = (floatx4){0.f, 0.f, 0.f, 0.f};
#pragma unroll
    for (int kc = 0; kc < 4; kc++)
#pragma unroll
      for (int mi = 0; mi < 2; mi++)
#pragma unroll
        for (int nj = 0; nj < 2; nj++)
          acc[mi][nj] = __builtin_amdgcn_mfma_f32_16x16x32_bf16(af[kc][mi], bfr[kc][nj], acc[mi][nj], 0, 0, 0);

    int gj[2]; float Aj[2], Bj[2], Cj[2], Dj[2];
#pragma unroll
    for (int nj = 0; nj < 2; nj++) {
      gj[nj] = nt * 128 + wn2 + nj * 16 + fc;
      Aj[nj] = jA[gj[nj]]; Bj[nj] = jB[gj[nj]]; Cj[nj] = jC[gj[nj]]; Dj[nj] = jc1[gj[nj]];
    }

#pragma unroll
    for (int mi = 0; mi < 2; mi++) {
#pragma unroll
      for (int rr = 0; rr < 4; rr++) {
        const int rl = wm2 + mi * 16 + fr4 + rr;
        const float qnr = qns[rl], crr = crs[rl], bqr = bqms[rl], q2r = q2bs[rl];
        const float l = lse_r[mi * 4 + rr];
#pragma unroll
        for (int nj = 0; nj < 2; nj++) {
          const float sq = fmaxf(qnr + Aj[nj] + bqr * Bj[nj] + q2r * Cj[nj]
                                 - 2.0f * acc[mi][nj][rr], 1e-12f);
          const float x = -__builtin_amdgcn_sqrtf(sq) + crr - Dj[nj] + t12s[rl + gj[nj]];
          const float vv = ((m0 + rl) < qlv && gj[nj] < klv) ? x : -1e9f;
          outp[(long)rl * TK + gj[nj]] = vv - l;
        }
      }
    }
  }
}

// ---------------- host ----------------
extern "C" void kernel_launch(void* const* d_in, const int* in_sizes, int n_in,
                              void* d_out, int out_size, void* d_ws, size_t ws_size,
                              hipStream_t stream)
{
  (void)in_sizes; (void)n_in; (void)out_size; (void)ws_size;
  const float* query = (const float*)d_in[0];
  const float* key   = (const float*)d_in[1];
  const int*   qlens = (const int*)d_in[2];
  const int*   klens = (const int*)d_in[3];
  const float* qc1_w = (const float*)d_in[4];
  const float* qc1_b = (const float*)d_in[5];
  const float* qc2_w = (const float*)d_in[6];
  const float* qc2_b = (const float*)d_in[7];
  const float* ql_w  = (const float*)d_in[8];
  const float* ql_b  = (const float*)d_in[9];
  const float* kc_w  = (const float*)d_in[10];
  const float* kc_b  = (const float*)d_in[11];
  const float* kl1_w = (const float*)d_in[12];
  const float* kl1_b = (const float*)d_in[13];
  const float* kl2_w = (const float*)d_in[14];
  const float* kl2_b = (const float*)d_in[15];

  size_t off = 0;
  char* ws = (char*)d_ws;
  auto alloc = [&](size_t bytes) -> char* {
    char* p = ws + off; off += (bytes + 255) & ~(size_t)255; return p;
  };
  // Front region (all dead by step 10): pool0 + qlw2 + kcp + TpT + pool = 69.2 MB
  u16* qc2w_bf = (u16*)alloc(2ull * H2 * H2);        //  8.39 MB
  u16* qc1T_bf = (u16*)alloc(2ull * QDP * H2);       //  0.52 MB
  u16* kl2w_bf = (u16*)alloc(2ull * HH * H2);        //  4.19 MB
  u16* kl1T_bf = (u16*)alloc(2ull * HH * H2);        //  4.19 MB
  u16* qT_bf   = (u16*)alloc(2ull * BB * QDP * 2048);//  8.39 MB   [pool0 = 25.69 MB]
  u16* kcolT_bf= (u16*)d_ws;                         // 25.17 MB overlay of pool0 (dead after X-GEMM)
  u16* Z2_bf   = (u16*)d_ws;                         //  4.19 MB overlay at front (written step 8)
  u16* qlw2_bf = (u16*)alloc(2ull * HH * 2048);      //  4.19 MB
  u16* kcp_bf  = (u16*)alloc(2ull * HH * 768);       //  1.57 MB
  u16* TpT_bf  = (u16*)alloc(2ull * H2 * HH);        //  4.19 MB  (rows = b*128+d, cols h)
  char* pool   = alloc(2ull * BB * HH * NKEY);       // 33.55 MB: split-K partials / X
  float* Pbuf  = (float*)pool;                       // fp32 partials (max 33.5 MB)
  u16* X_bf    = (u16*)pool;                         // X[b] (1024h x 768r) bf16, 25.2 MB
  // Region B: persistent through step 10
  float* tbl  = (float*)alloc(4ull * 8192);
  u16* Wq_bf  = (u16*)alloc(2ull * H2 * QDP);
  u16* Wk_bf  = (u16*)alloc(2ull * HH * NKEY);
  float* bqm  = (float*)alloc(4ull * H2);
  float* bkv  = (float*)alloc(4ull * HH);
  float* s1v  = (float*)alloc(4ull * HH);
  float* s0v  = (float*)alloc(4ull * HH);
  float* wsum = (float*)alloc(4ull * HH);
  float* colsum1 = (float*)alloc(4ull * H2);
  u16* K3_bf  = (u16*)alloc(2ull * BB * TK * HH);    // 33.55 MB
  float* qnv  = (float*)alloc(4ull * BB * TQ);
  float* knv  = (float*)alloc(4ull * BB * TK);
  float* ybv  = (float*)alloc(4ull * BB * TK);
  float* y1v  = (float*)alloc(4ull * BB * TK);
  float* y0v  = (float*)alloc(4ull * BB * TK);
  float* u0v  = (float*)alloc(4ull * BB * QDP);
  float* u1v  = (float*)alloc(4ull * BB * QDP);
  float* u2v  = (float*)alloc(4ull * BB * QDP);
  float* c1v  = (float*)alloc(4ull * BB * TK);
  float* crowv= (float*)alloc(4ull * BB * TQ);
  float* t12v = (float*)alloc(4ull * BB * T12N);
  float* scv  = (float*)alloc(256);
  // Parked in d_out (consumed by step 6, before step 10 overwrites d_out):
  float* WqG  = (float*)d_out;                              // 16.78 MB fp32
  u16* G_bf   = (u16*)((char*)d_out + 16777216);            //  0.52 MB

  // 1. prep (casts, qlw2, kcp, colsum, lgamma) + tiled transposes + bias folds
  prep_all_k<<<37920, 256, 0, stream>>>(qc2_w, kl2_w, ql_w, kc_w, kl1_w,
                                        qc2w_bf, kl2w_bf, qlw2_bf, kcp_bf, colsum1, tbl);
  tpack_k<<<1600, 256, 0, stream>>>(kl1_w, qc1_w, query, kl1T_bf, qc1T_bf, qT_bf);
  fold_bias_k<<<4096, 256, 0, stream>>>(qc2_w, qc1_b, qc2_b, kl2_w, kl1_b, kl2_b, ql_w, colsum1,
                                        bqm, bkv, s1v, s0v, wsum);

  // 2. Wq = qc2_w @ qc1_w-fold (2048x128), split-K 16 (KS=128)
  gemm_bt<1><<<dim3(1, 16, 16), 256, 0, stream>>>(qc2w_bf, qc1T_bf, Pbuf, H2, QDP, 128,
      H2, H2, 0, 16, 0, 0, (long)H2 * QDP, 0,
      nullptr, nullptr, nullptr, nullptr, nullptr, nullptr);
  reduce_bk_k<<<256, 256, 0, stream>>>(Pbuf, Wq_bf, (long)H2 * QDP, 16, (long)H2 * QDP);

  // 3. Wk = kl2_w @ kl1_w-fold (1024x1024), split-K 8 (KS=256)
  gemm_bt<1><<<dim3(8, 8, 8), 256, 0, stream>>>(kl2w_bf, kl1T_bf, Pbuf, HH, NKEY, 256,
      H2, H2, 0, 8, 0, 0, (long)HH * NKEY, 0,
      nullptr, nullptr, nullptr, nullptr, nullptr, nullptr);
  reduce_bk_k<<<1024, 256, 0, stream>>>(Pbuf, Wk_bf, (long)HH * NKEY, 8, (long)HH * NKEY);

  // 4. TpT (2048 x 1024) = qT @ qlw2^T, split-K 4 (KS=512)
  gemm_bt<1><<<dim3(8, 16, 4), 256, 0, stream>>>(qT_bf, qlw2_bf, Pbuf, H2, HH, 512,
      2048, 2048, 0, 4, 0, 0, (long)H2 * HH, 0,
      nullptr, nullptr, nullptr, nullptr, nullptr, nullptr);
  reduce_bk_k<<<2048, 256, 0, stream>>>(Pbuf, TpT_bf, (long)H2 * HH, 4, (long)H2 * HH);

  // 5. G[b] = TpT_b @ TpT_b^T (128x128 Gram per batch), split-K 8 (KS=128)
  gemm_bt<1><<<dim3(1, 1, 128), 256, 0, stream>>>(TpT_bf, TpT_bf, Pbuf, 128, 128, 128,
      HH, HH, 0, 8, (long)QDP * HH, (long)QDP * HH, 128 * 128, 0,
      nullptr, nullptr, nullptr, nullptr, nullptr, nullptr);
  reduce_bk_k<<<256, 256, 0, stream>>>(Pbuf, G_bf, 128 * 128, 8, (long)BB * 128 * 128);

  // 6. WqG[b] = Wq @ G[b]  (fp32, G symmetric) ; u-vectors + scalars + prior tables ; qn
  gemm_bt<1><<<dim3(1, 16, 16), 256, 0, stream>>>(Wq_bf, G_bf, WqG, H2, QDP, QDP,
      QDP, QDP, 0, 1, 0, (long)QDP * QDP, (long)H2 * QDP, 0,
      nullptr, nullptr, nullptr, nullptr, nullptr, nullptr);
  u_k<<<BB * QDP + 6 + 64 + 128 + 192, 256, 0, stream>>>(TpT_bf, ql_b, s1v, s0v, tbl, qlens, klens,
                                                         u0v, u1v, u2v, scv, c1v, crowv, t12v);
  qn_k<<<BB * TQ / 2, 256, 0, stream>>>(Wq_bf, WqG, u0v, u1v, u2v, bqm, qc2_b, scv, qnv);

  // 7. key branch, reassociated: X[b] = Wk @ kcolT[b]^T ; K3[b] = kcp @ X[b]^T + biases
  pack_kcolT_k<<<1024, 256, 0, stream>>>(key, kcolT_bf);
  gemm_bt<0><<<dim3(6, 8, BB), 256, 0, stream>>>(Wk_bf, kcolT_bf, X_bf, HH, 768, NKEY,
      NKEY, NKEY, 0, 1, 0, (long)768 * NKEY, (long)HH * 768, 0,
      nullptr, nullptr, nullptr, nullptr, nullptr, nullptr);
  gemm_bt<0><<<dim3(8, 8, BB), 256, 0, stream>>>(kcp_bf, X_bf, K3_bf, HH, NKEY, 768,
      768, 768, 1, 1, 0, (long)HH * 768, (long)TK * HH, 0,
      bkv, nullptr, kc_b, wsum, nullptr, nullptr);

  // 8. Z2[b] = K3[b] @ TpT_b^T (1024x128), split-K 2 (KS=512) -> Pbuf -> bf16 at d_ws front
  gemm_bt<1><<<dim3(8, 1, 32), 256, 0, stream>>>(K3_bf, TpT_bf, Pbuf, TK, QDP, 512,
      HH, HH, 1, 2, (long)TK * HH, (long)QDP * HH, (long)TK * QDP, 0,
      nullptr, nullptr, nullptr, nullptr, nullptr, nullptr);
  reduce_bk_k<<<2048, 256, 0, stream>>>(Pbuf, Z2_bf, (long)TK * QDP, 2, (long)BB * TK * QDP);

  // 9. K3 row norms + per-row bias dots (yb, y1, y0)
  rownormk_k<<<BB * TK, 256, 0, stream>>>(K3_bf, ql_b, s1v, s0v, knv, ybv, y1v, y0v);

  // 10. fused S-GEMM + dist + prior + log_softmax -> d_out (fp32), no intermediate
  smax_k<<<dim3(16, 16), 1024, 0, stream>>>(Wq_bf, Z2_bf, (float*)d_out,
      ybv, y1v, y0v, bqm, qc2_b, qnv, knv, c1v, crowv, t12v, qlens, klens);
}

// Round 7
// 611.473 us; speedup vs baseline: 1.0374x; 1.0089x over previous
//
#include <hip/hip_runtime.h>
#include <math.h>

typedef unsigned short u16;
typedef float floatx4 __attribute__((ext_vector_type(4)));
typedef __bf16 bf16x8 __attribute__((ext_vector_type(8)));

// Problem constants
#define BB   16
#define TQ   2048   // query length after convs (= 2H)
#define TK   1024   // key rows (= H)
#define HH   1024   // H
#define H2   2048   // 2H
#define QD   80
#define QDP  128    // QD padded to tile width (zero-filled)
#define KD   256
#define NQ   2044
#define NKEY 1024
#define T12N 3072   // t12 table stride per batch (covers s = i+j in [0, 3071))

__device__ __forceinline__ u16 f2bf(float f) {
  unsigned int u = __float_as_uint(f);
  u = u + 0x7fffu + ((u >> 16) & 1u);
  return (u16)(u >> 16);
}
__device__ __forceinline__ float bf2f(u16 s) {
  return __uint_as_float(((unsigned int)s) << 16);
}
__device__ __forceinline__ float tgf(const float* __restrict__ tbl, int x) {
  return tbl[(x < 8191) ? (x < 0 ? 0 : x) : 8191];
}

// ---------------- fused prep: elementwise packs + kl1 row-sums + lgamma table ----------------
// segments (blocks): qc2w 16384 | kl2w 8192 | qlw2 8192 | kcp 3072 | colsum 2048 | lgamma 32
//   => grid 37920
__global__ __launch_bounds__(256) void prep_all_k(
    const float* __restrict__ qc2_w, const float* __restrict__ kl2_w,
    const float* __restrict__ ql_w, const float* __restrict__ kc_w,
    const float* __restrict__ kl1_w,
    u16* __restrict__ qc2w, u16* __restrict__ kl2w, u16* __restrict__ qlw2,
    u16* __restrict__ kcp, float* __restrict__ colsum1, float* __restrict__ tbl)
{
  long b = blockIdx.x;
  const int t = threadIdx.x;
  __shared__ float red[256];
  if (b < 16384) {                       // qc2w: cast (2048x2048)
    long i = b * 256 + t; qc2w[i] = f2bf(qc2_w[i]); return;
  }
  b -= 16384;
  if (b < 8192) {                        // kl2w: cast (1024x2048)
    long i = b * 256 + t; kl2w[i] = f2bf(kl2_w[i]); return;
  }
  b -= 8192;
  if (b < 8192) {                        // qlw2[h,n] = ql_w[h,n+2], n<2044 else 0
    long i = b * 256 + t;
    int n = (int)(i & 2047);
    int h = (int)(i >> 11);
    qlw2[i] = (n < NQ) ? f2bf(ql_w[(long)h * H2 + n + 2]) : (u16)0; return;
  }
  b -= 8192;
  if (b < 3072) {                        // kcp: (1024,256,3)->(1024,768), kk=t*256+d
    long i = b * 256 + t;
    int r = (int)(i % 768);
    int o = (int)(i / 768);
    int tt = r >> 8, d = r & 255;
    kcp[i] = f2bf(kc_w[((long)o * KD + d) * 3 + tt]); return;
  }
  b -= 3072;
  if (b < 2048) {                        // colsum1[o] = sum_n kl1_w[o,n]
    const float* row = kl1_w + b * (long)HH;
    float s = row[t] + row[t + 256] + row[t + 512] + row[t + 768];
    red[t] = s; __syncthreads();
    for (int st = 128; st > 0; st >>= 1) { if (t < st) red[t] += red[t + st]; __syncthreads(); }
    if (!t) colsum1[b] = red[0];
    return;
  }
  b -= 2048;
  { int i = (int)(b * 256 + t); if (i < 8192) tbl[i] = i ? (float)lgamma((double)i) : 0.0f; }
}

// ---------------- tiled transposes (fp32 src -> bf16 dst), 64x64 LDS tiles ----------------
// segments: kl1T 512 | qc1T 64 | qT 1024  => grid 1600
__global__ __launch_bounds__(256) void tpack_k(
    const float* __restrict__ kl1_w, const float* __restrict__ qc1_w,
    const float* __restrict__ query,
    u16* __restrict__ kl1T, u16* __restrict__ qc1T, u16* __restrict__ qT)
{
  __shared__ float tile[64][65];
  int bid = blockIdx.x;
  const int tid = threadIdx.x;
  const int r4 = tid >> 6, c = tid & 63;
  const float* src; u16* dst;
  int sr0, sc0, srcR, srcC, srcStride, dstC;
  if (bid < 512) {                       // kl1T: (2048x1024) -> (1024x2048)
    sr0 = (bid >> 4) * 64; sc0 = (bid & 15) * 64;
    src = kl1_w; srcR = 2048; srcC = 1024; srcStride = 1024;
    dst = kl1T; dstC = 2048;
  } else if ((bid -= 512) < 64) {        // qc1T: (2048x80) -> (128x2048)
    sr0 = (bid >> 1) * 64; sc0 = (bid & 1) * 64;
    src = qc1_w; srcR = 2048; srcC = QD; srcStride = QD;
    dst = qc1T; dstC = 2048;
  } else {                               // qT: per b, (2044x80) -> (128x2048)
    bid -= 64;
    const int b16 = bid >> 6, r = bid & 63;
    sr0 = (r >> 1) * 64; sc0 = (r & 1) * 64;
    src = query + (long)b16 * NQ * QD; srcR = NQ; srcC = QD; srcStride = QD;
    dst = qT + (long)b16 * QDP * 2048; dstC = 2048;
  }
#pragma unroll
  for (int rr = r4; rr < 64; rr += 4) {
    const int gr = sr0 + rr, gc = sc0 + c;
    tile[rr][c] = (gr < srcR && gc < srcC) ? src[(long)gr * srcStride + gc] : 0.f;
  }
  __syncthreads();
#pragma unroll
  for (int rr = r4; rr < 64; rr += 4)
    dst[(long)(sc0 + rr) * dstC + sr0 + c] = f2bf(tile[c][rr]);
}

// ---------------- transposed im2col: kcolT[b][(t,d)][n] = key[b, n+t-1, d] ----------------
// grid 1024: b = bid>>6; tile (m0,d0) of key[b]; writes 3 shifted transposed tiles.
__global__ __launch_bounds__(256) void pack_kcolT_k(const float* __restrict__ key, u16* __restrict__ out) {
  __shared__ float tile[64][65];
  const int bid = blockIdx.x, tid = threadIdx.x;
  const int b = bid >> 6, r = bid & 63;
  const int m0 = (r >> 2) * 64;          // key row (position) tile
  const int d0 = (r & 3) * 64;           // key col (channel) tile
  const int r4 = tid >> 6, c = tid & 63;
#pragma unroll
  for (int rr = r4; rr < 64; rr += 4)
    tile[rr][c] = key[((long)b * NKEY + m0 + rr) * KD + d0 + c];
  __syncthreads();
#pragma unroll
  for (int t = 0; t < 3; t++) {
    const int n = m0 + 1 - t + c;
    if (n >= 0 && n < NKEY) {
#pragma unroll
      for (int rr = r4; rr < 64; rr += 4)
        out[((long)b * 768 + t * 256 + d0 + rr) * NKEY + n] = f2bf(tile[c][rr]);
    }
  }
  // zero the never-written boundary columns: (t=0, n=0) and (t=2, n=1023)
  if (m0 == 0 && c == 0) {
#pragma unroll
    for (int rr = r4; rr < 64; rr += 4)
      out[((long)b * 768 + d0 + rr) * NKEY + 0] = (u16)0;
  }
  if (m0 == 960 && c == 0) {
#pragma unroll
    for (int rr = r4; rr < 64; rr += 4)
      out[((long)b * 768 + 512 + d0 + rr) * NKEY + (NKEY - 1)] = (u16)0;
  }
}

// ---------------- fused bias folds (+ wsum) ----------------
// grid = H2 (bqm) + HH (bkv+wsum) + HH (s1/s0) = 4096
__global__ __launch_bounds__(256) void fold_bias_k(
    const float* __restrict__ qc2_w, const float* __restrict__ qc1_b, const float* __restrict__ qc2_b,
    const float* __restrict__ kl2_w, const float* __restrict__ kl1_b, const float* __restrict__ kl2_b,
    const float* __restrict__ ql_w, const float* __restrict__ colsum1,
    float* __restrict__ bqm, float* __restrict__ bkv, float* __restrict__ s1v, float* __restrict__ s0v,
    float* __restrict__ wsum)
{
  const int bid = blockIdx.x, t = threadIdx.x;
  float s = 0.f, s2 = 0.f;
  if (bid < H2) {
    const float* row = qc2_w + (long)bid * H2;
    for (int k = t; k < H2; k += 256) s += row[k] * qc1_b[k];
  } else if (bid < H2 + HH) {
    const float* row = kl2_w + (long)(bid - H2) * H2;
    for (int k = t; k < H2; k += 256) { const float rv = row[k]; s += rv * kl1_b[k]; s2 += rv * colsum1[k]; }
  } else {
    const float* row = ql_w + (long)(bid - H2 - HH) * H2;
    for (int m = 1 + t; m <= H2 - 2; m += 256) s += row[m];
  }
  __shared__ float red[256];
  __shared__ float red2[256];
  red[t] = s; red2[t] = s2; __syncthreads();
  for (int st = 128; st > 0; st >>= 1) {
    if (t < st) { red[t] += red[t + st]; red2[t] += red2[t + st]; }
    __syncthreads();
  }
  if (!t) {
    if (bid < H2) bqm[bid] = red[0] + qc2_b[bid];
    else if (bid < H2 + HH) { bkv[bid - H2] = red[0] + kl2_b[bid - H2]; wsum[bid - H2] = red2[0]; }
    else {
      int h = bid - H2 - HH;
      s1v[h] = red[0];
      s0v[h] = ql_w[(long)h * H2] + ql_w[(long)h * H2 + H2 - 1];
    }
  }
}

// ---------------- MFMA GEMM: C[b] = A[b] @ B[b]^T (+ biases) ----------------
// Requires: M%128==0, N%128==0, K%32==0, lda/ldb%8==0, 16B-aligned bases.
// kspl: blockIdx.z decodes as (batch = z/kspl, kslice = z%kspl).
// OUTF32 = 1: write fp32 raw; OUTF32 = 0: bf16 with epilogue
//   + colb[n] + rowb[m] + r1m[m]*r1n[n] + r2m[m]*r2n[n]  (null = skip);
//   colb/r1n/r2n advance by batch*sN (per-batch n-side vectors).
__device__ __forceinline__ void gld_lds16(const u16* g, u16* l) {
  __builtin_amdgcn_global_load_lds((const __attribute__((address_space(1))) void*)g,
                                   (__attribute__((address_space(3))) void*)l, 16, 0, 0);
}

template<int OUTF32>
__global__ __launch_bounds__(256) void gemm_bt(
    const u16* __restrict__ A, const u16* __restrict__ B, void* __restrict__ Cv,
    int M, int N, int K, int lda, int ldb, int swap, int kspl,
    long sA, long sB, long sC, long sN,
    const float* __restrict__ colb, const float* __restrict__ rowb,
    const float* __restrict__ r1m, const float* __restrict__ r1n,
    const float* __restrict__ r2m, const float* __restrict__ r2n)
{
  __shared__ __align__(16) u16 As[128 * 32];   // 8 KB
  __shared__ __align__(16) u16 Bs[128 * 32];   // 8 KB
  const int bz = blockIdx.z;
  const int bb_ = (kspl > 1) ? bz / kspl : bz;
  const int ks_ = (kspl > 1) ? bz - bb_ * kspl : 0;
  const int tid  = threadIdx.x;
  const int lane = tid & 63;
  const int wv = tid >> 6;                // wave 0..3
  const int wm = ((tid >> 7) & 1) * 64;   // wave row offset
  const int wn = ((tid >> 6) & 1) * 64;   // wave col offset
  const int m0 = (swap ? blockIdx.x : blockIdx.y) * 128;
  const int n0 = (swap ? blockIdx.y : blockIdx.x) * 128;

  // staging: wave wv covers rows [wv*32, wv*32+32) of both tiles, 2 instrs of 16 rows each
  const int srow = wv * 32 + (lane >> 2);       // lane's source row within tile (first instr)
  const int scol = (lane & 3) << 3;             // 0,8,16,24
  const u16* ga = A + bb_ * sA + (long)ks_ * K + (long)(m0 + srow) * lda + scol;
  const u16* gb = B + bb_ * sB + (long)ks_ * K + (long)(n0 + srow) * ldb + scol;
  u16* la0 = &As[(wv * 32) * 32];
  u16* la1 = &As[(wv * 32 + 16) * 32];
  u16* lb0 = &Bs[(wv * 32) * 32];
  u16* lb1 = &Bs[(wv * 32 + 16) * 32];
  const long a16 = (long)16 * lda;
  const long b16 = (long)16 * ldb;

  floatx4 acc[4][4];
#pragma unroll
  for (int a_ = 0; a_ < 4; a_++)
#pragma unroll
    for (int b_ = 0; b_ < 4; b_++) acc[a_][b_] = (floatx4){0.f, 0.f, 0.f, 0.f};

  const int fr = lane & 15;         // frag row/col within 16
  const int fk = (lane >> 4) << 3;  // frag k offset

  for (int kb = 0; kb < K; kb += 32) {
    gld_lds16(ga,       la0);
    gld_lds16(ga + a16, la1);
    gld_lds16(gb,       lb0);
    gld_lds16(gb + b16, lb1);
    ga += 32; gb += 32;
    __syncthreads();
    bf16x8 af[4], bfr[4];
#pragma unroll
    for (int mi = 0; mi < 4; mi++)
      af[mi] = *reinterpret_cast<const bf16x8*>(&As[(wm + mi * 16 + fr) * 32 + fk]);
#pragma unroll
    for (int ni = 0; ni < 4; ni++)
      bfr[ni] = *reinterpret_cast<const bf16x8*>(&Bs[(wn + ni * 16 + fr) * 32 + fk]);
#pragma unroll
    for (int mi = 0; mi < 4; mi++)
#pragma unroll
      for (int ni = 0; ni < 4; ni++)
        acc[mi][ni] = __builtin_amdgcn_mfma_f32_16x16x32_bf16(af[mi], bfr[ni], acc[mi][ni], 0, 0, 0);
    __syncthreads();
  }

  // epilogue: C/D layout col=lane&15, row=(lane>>4)*4+reg  [m89-verified]
  const int fr4 = (lane >> 4) << 2;
  const int fc  = lane & 15;
  u16*   Cb16 = (u16*)Cv + (long)bz * sC;
  float* Cb32 = (float*)Cv + (long)bz * sC;
  const float* cbp  = colb ? colb + (long)bb_ * sN : nullptr;
  const float* r1np = r1n ? r1n + (long)bb_ * sN : nullptr;
  const float* r2np = r2n ? r2n + (long)bb_ * sN : nullptr;
#pragma unroll
  for (int mi = 0; mi < 4; mi++) {
#pragma unroll
    for (int ni = 0; ni < 4; ni++) {
      const int gm0 = m0 + wm + mi * 16 + fr4;
      const int gn  = n0 + wn + ni * 16 + fc;
      const float cbv  = cbp ? cbp[gn] : 0.f;
      const float r1nv = r1np ? r1np[gn] : 0.f;
      const float r2nv = r2np ? r2np[gn] : 0.f;
#pragma unroll
      for (int rr = 0; rr < 4; rr++) {
        const int gm = gm0 + rr;
        float v = acc[mi][ni][rr] + cbv;
        if (rowb) v += rowb[gm];
        if (r1m)  v += r1m[gm] * r1nv;
        if (r2m)  v += r2m[gm] * r2nv;
        if (OUTF32) Cb32[(long)gm * N + gn] = v;
        else        Cb16[(long)gm * N + gn] = f2bf(v);
      }
    }
  }
}

// ---------------- split-K reduce (batch-major planes) ----------------
__global__ __launch_bounds__(256) void reduce_bk_k(const float* __restrict__ P, u16* __restrict__ out,
                                                   long chunk, int S, long total) {
  long j = ((long)blockIdx.x * 256 + threadIdx.x) * 4;
  if (j >= total) return;
  long b = j / chunk;
  const float* p = P + j + b * chunk * (S - 1);
  float4 s = *reinterpret_cast<const float4*>(p);
  for (int t = 1; t < S; t++) {
    const float4 v = *reinterpret_cast<const float4*>(p + (long)t * chunk);
    s.x += v.x; s.y += v.y; s.z += v.z; s.w += v.w;
  }
  union { u16 h[4]; uint2 u; } o;
  o.h[0] = f2bf(s.x); o.h[1] = f2bf(s.y); o.h[2] = f2bf(s.z); o.h[3] = f2bf(s.w);
  *reinterpret_cast<uint2*>(out + j) = o.u;
}

// ---------------- u-vectors + bias-cross scalars + prior tables ----------------
// blocks 0..2047:      u{0,1,2}[b*128+d] = sum_h TpT[b*128+d, h] * {ql_b, s1v, s0v}[h]
// blocks 2048..2053:   sc[idx] pair dots
// blocks 2054..2117:   c1[b][j]  = lg(j+1) + lg(n_-j+1)
// blocks 2118..2245:   crow[b][i] = lg(n_+1)+lg(i+1+bb)-lg(i+1)-lg(bb)-lg(i+1+n_+bb)
// blocks 2246..2437:   t12[b][s] = lg(s+1) + lg(n_+ql-s)        (s = i+j)
__global__ __launch_bounds__(256) void u_k(
    const u16* __restrict__ TpT, const float* __restrict__ qlb,
    const float* __restrict__ s1, const float* __restrict__ s0,
    const float* __restrict__ tbl, const int* __restrict__ qlens, const int* __restrict__ klens,
    float* __restrict__ u0, float* __restrict__ u1, float* __restrict__ u2,
    float* __restrict__ sc, float* __restrict__ c1,
    float* __restrict__ crow, float* __restrict__ t12)
{
  const int bid = blockIdx.x, t = threadIdx.x;
  __shared__ float4 red[256];
  if (bid < BB * QDP) {
    uint2 v = reinterpret_cast<const uint2*>(TpT + (long)bid * HH)[t];
    float a0 = bf2f((u16)(v.x & 0xffff)), a1 = bf2f((u16)(v.x >> 16));
    float a2 = bf2f((u16)(v.y & 0xffff)), a3 = bf2f((u16)(v.y >> 16));
    float4 q  = reinterpret_cast<const float4*>(qlb)[t];
    float4 w1 = reinterpret_cast<const float4*>(s1)[t];
    float4 w0 = reinterpret_cast<const float4*>(s0)[t];
    float4 s;
    s.x = a0 * q.x  + a1 * q.y  + a2 * q.z  + a3 * q.w;
    s.y = a0 * w1.x + a1 * w1.y + a2 * w1.z + a3 * w1.w;
    s.z = a0 * w0.x + a1 * w0.y + a2 * w0.z + a3 * w0.w;
    s.w = 0.f;
    red[t] = s; __syncthreads();
    for (int st = 128; st > 0; st >>= 1) {
      if (t < st) { red[t].x += red[t + st].x; red[t].y += red[t + st].y; red[t].z += red[t + st].z; }
      __syncthreads();
    }
    if (!t) { u0[bid] = red[0].x; u1[bid] = red[0].y; u2[bid] = red[0].z; }
  } else if (bid < BB * QDP + 6) {
    const int idx = bid - BB * QDP;
    const float* X = (idx == 1 || idx == 5) ? s1 : (idx == 2) ? s0 : qlb;
    const float* Y = (idx == 1 || idx == 3) ? s1 : (idx == 0) ? qlb : s0;
    float4 x = reinterpret_cast<const float4*>(X)[t];
    float4 y = reinterpret_cast<const float4*>(Y)[t];
    float4 s; s.x = x.x * y.x + x.y * y.y + x.z * y.z + x.w * y.w; s.y = s.z = s.w = 0.f;
    red[t] = s; __syncthreads();
    for (int st = 128; st > 0; st >>= 1) {
      if (t < st) red[t].x += red[t + st].x;
      __syncthreads();
    }
    if (!t) sc[idx] = red[0].x;
  } else if (bid < BB * QDP + 6 + 64) {
    const int idx = bid - (BB * QDP + 6);
    const int b = idx >> 2;
    const int j = ((idx & 3) << 8) | t;
    const int kl = klens[b];
    const int n_ = (kl - 1 > 0) ? kl - 1 : 0;
    c1[b * TK + j] = tgf(tbl, j + 1) + tgf(tbl, n_ - j + 1);
  } else if (bid < BB * QDP + 6 + 64 + 128) {
    const int idx = bid - (BB * QDP + 6 + 64);
    const int b = idx >> 3;
    const int i = ((idx & 7) << 8) | t;
    const int ql = qlens[b], kl = klens[b];
    const int n_ = (kl - 1 > 0) ? kl - 1 : 0;
    const int bb = (ql - i > 1) ? ql - i : 1;
    crow[b * TQ + i] = tgf(tbl, n_ + 1) + tgf(tbl, i + 1 + bb) - tgf(tbl, i + 1)
                     - tgf(tbl, bb) - tgf(tbl, i + 1 + n_ + bb);
  } else {
    const int idx = bid - (BB * QDP + 6 + 64 + 128);
    const int b = idx / 12;
    const int s = (idx - b * 12) * 256 + t;
    const int ql = qlens[b], kl = klens[b];
    const int n_ = (kl - 1 > 0) ? kl - 1 : 0;
    t12[b * T12N + s] = tgf(tbl, s + 1) + tgf(tbl, n_ + ql - s);
  }
}

// ---------------- qn via Gram quadratic form ----------------
__global__ __launch_bounds__(256) void qn_k(
    const u16* __restrict__ Wq, const float* __restrict__ WqG,
    const float* __restrict__ u0, const float* __restrict__ u1, const float* __restrict__ u2,
    const float* __restrict__ bqm, const float* __restrict__ qc2_b,
    const float* __restrict__ sc, float* __restrict__ qn)
{
  const int bx = blockIdx.x, t = threadIdx.x;
  const int b = bx >> 10;
  const int i = ((bx & 1023) << 1) | (t >> 7);
  const int d = t & 127;
  const float w  = bf2f(Wq[(long)i * QDP + d]);
  const float g  = WqG[((long)b * H2 + i) * QDP + d];
  const float bq = bqm[i], q2 = qc2_b[i];
  const float uu = u0[b * QDP + d] + bq * u1[b * QDP + d] + q2 * u2[b * QDP + d];
  __shared__ float red[256];
  red[t] = w * (g + 2.f * uu); __syncthreads();
  for (int s = 64; s > 0; s >>= 1) { if ((t & 127) < s) red[t] += red[t + s]; __syncthreads(); }
  if (d == 0) {
    const float cst = sc[0] + bq * bq * sc[1] + q2 * q2 * sc[2]
                    + 2.f * (bq * sc[3] + q2 * sc[4] + bq * q2 * sc[5]);
    qn[b * TQ + i] = red[t] + cst;
  }
}

// ---------------- K3 row norms + the three per-row bias dots ----------------
__global__ __launch_bounds__(256) void rownormk_k(
    const u16* __restrict__ K3, const float* __restrict__ qlb,
    const float* __restrict__ s1, const float* __restrict__ s0,
    float* __restrict__ kn, float* __restrict__ yb, float* __restrict__ y1, float* __restrict__ y0)
{
  const long r = blockIdx.x;
  const int t = threadIdx.x;
  uint2 v = reinterpret_cast<const uint2*>(K3 + r * HH)[t];
  float a0 = bf2f((u16)(v.x & 0xffff)), a1 = bf2f((u16)(v.x >> 16));
  float a2 = bf2f((u16)(v.y & 0xffff)), a3 = bf2f((u16)(v.y >> 16));
  float4 q  = reinterpret_cast<const float4*>(qlb)[t];
  float4 w1 = reinterpret_cast<const float4*>(s1)[t];
  float4 w0 = reinterpret_cast<const float4*>(s0)[t];
  float4 s;
  s.x = a0 * a0   + a1 * a1   + a2 * a2   + a3 * a3;
  s.y = a0 * q.x  + a1 * q.y  + a2 * q.z  + a3 * q.w;
  s.z = a0 * w1.x + a1 * w1.y + a2 * w1.z + a3 * w1.w;
  s.w = a0 * w0.x + a1 * w0.y + a2 * w0.z + a3 * w0.w;
  __shared__ float4 red[256];
  red[t] = s; __syncthreads();
  for (int st = 128; st > 0; st >>= 1) {
    if (t < st) {
      red[t].x += red[t + st].x; red[t].y += red[t + st].y;
      red[t].z += red[t + st].z; red[t].w += red[t + st].w;
    }
    __syncthreads();
  }
  if (!t) { kn[r] = red[0].x; yb[r] = red[0].y; y1[r] = red[0].z; y0[r] = red[0].w; }
}

// ---------------- fused S-GEMM + dist + prior + log_softmax (recompute, no v traffic) ----------------
// Block (b, mt): 128 rows x 1024 cols. 1024 threads = 16 waves (4m x 4n), 1 block/CU.
// Grid (16 b, 16 mt): linear id = b + 16*mt -> XCD = b%8 (round-robin), so all 16
// mt-blocks of a batch share one XCD's L2 -> Z2[b] fetched from HBM once per XCD.
// Fixed-max softmax: v <= 0 always (dist<=0, log-pmf<=0), so pass 0 sums exp2(v*L2E)
// directly (no running max); empty-row fallback lse = -1e9 + log(TK) matches ref.
// Pass 1 recomputes v, subtracts lse, stages per-wave 32x32 tile in LDS (stride 36,
// conflict-benign), stores full 128B lines via dwordx4 (no cross-wave barriers).
#define L2E 1.4426950408889634f
__global__ __launch_bounds__(1024) void smax_k(
    const u16* __restrict__ Wq, const u16* __restrict__ Z2, float* __restrict__ out,
    const float* __restrict__ ybv, const float* __restrict__ y1v, const float* __restrict__ y0v,
    const float* __restrict__ bqmv, const float* __restrict__ qc2_b,
    const float* __restrict__ qnv, const float* __restrict__ knv, const float* __restrict__ c1v,
    const float* __restrict__ crowv, const float* __restrict__ t12v,
    const int* __restrict__ qlens, const int* __restrict__ klens)
{
  __shared__ __align__(16) float wst[16][32 * 36];   // 73.7 KB per-wave store staging
  __shared__ float t12s[1152];
  __shared__ float jA[1024], jB[1024], jC[1024], jc1[1024];
  __shared__ float qns[128], crs[128], bqms[128], q2bs[128];
  __shared__ float lseb[4][128];
  __shared__ float lsef[128];

  const int b = blockIdx.x, mt = blockIdx.y;
  const int m0 = mt * 128;
  const int t = threadIdx.x;
  const int w = t >> 6, lane = t & 63;
  const int wm2 = (w >> 2) * 32;      // 0,32,64,96
  const int wn2 = (w & 3) * 32;       // 0,32,64,96 (within each 128-col n-tile)
  const int fr = lane & 15, fk = (lane >> 4) << 3;
  const int fr4 = (lane >> 4) << 2, fc = lane & 15;
  const int qlv = qlens[b], klv = klens[b];

  if (t < 128) {
    qns[t]  = qnv[(long)b * TQ + m0 + t];
    crs[t]  = crowv[(long)b * TQ + m0 + t];
    bqms[t] = bqmv[m0 + t];
    q2bs[t] = qc2_b[m0 + t];
  }
  for (int k = t; k < 1152; k += 1024) t12s[k] = t12v[(long)b * T12N + m0 + k];
  {
    const int j = t;   // 1024 threads <-> 1024 columns
    const float kn = knv[(long)b * TK + j];
    const float yb = ybv[(long)b * TK + j];
    const float y1 = y1v[(long)b * TK + j];
    const float y0 = y0v[(long)b * TK + j];
    jA[j]  = kn - 2.f * yb;
    jB[j]  = -2.f * y1;
    jC[j]  = -2.f * y0;
    jc1[j] = c1v[(long)b * TK + j];
  }

  // A fragments in registers: Wq rows [m0+wm2, +32), K=128
  bf16x8 af[4][2];
#pragma unroll
  for (int kc = 0; kc < 4; kc++)
#pragma unroll
    for (int mi = 0; mi < 2; mi++)
      af[kc][mi] = *reinterpret_cast<const bf16x8*>(
          Wq + (long)(m0 + wm2 + mi * 16 + fr) * QDP + kc * 32 + fk);

  const u16* Zb = Z2 + (long)b * TK * QDP;
  float* outp = out + (long)b * TQ * TK + (long)m0 * TK;

  float s_[8];                        // 2 mi x 4 rr, fixed-max partial sums
#pragma unroll
  for (int ri = 0; ri < 8; ri++) s_[ri] = 0.f;

  __syncthreads();

  // -------- pass 0: sum exp2(v*L2E), no max tracking, no stores, no barriers --------
  for (int nt = 0; nt < 8; nt++) {
    bf16x8 bfr[4][2];
#pragma unroll
    for (int kc = 0; kc < 4; kc++)
#pragma unroll
      for (int nj = 0; nj < 2; nj++)
        bfr[kc][nj] = *reinterpret_cast<const bf16x8*>(
            Zb + (long)(nt * 128 + wn2 + nj * 16 + fr) * QDP + kc * 32 + fk);

    floatx4 acc[2][2];
#pragma unroll
    for (int mi = 0; mi < 2; mi++)
#pragma unroll
      for (int nj = 0; nj < 2; nj++) acc[mi][nj] = (floatx4){0.f, 0.f, 0.f, 0.f};
#pragma unroll
    for (int kc = 0; kc < 4; kc++)
#pragma unroll
      for (int mi = 0; mi < 2; mi++)
#pragma unroll
        for (int nj = 0; nj < 2; nj++)
          acc[mi][nj] = __builtin_amdgcn_mfma_f32_16x16x32_bf16(af[kc][mi], bfr[kc][nj], acc[mi][nj], 0, 0, 0);

    int gj[2]; float Aj[2], Bj[2], Cj[2], Dj[2];
#pragma unroll
    for (int nj = 0; nj < 2; nj++) {
      gj[nj] = nt * 128 + wn2 + nj * 16 + fc;
      Aj[nj] = jA[gj[nj]]; Bj[nj] = jB[gj[nj]]; Cj[nj] = jC[gj[nj]]; Dj[nj] = jc1[gj[nj]];
    }

#pragma unroll
    for (int mi = 0; mi < 2; mi++) {
#pragma unroll
      for (int rr = 0; rr < 4; rr++) {
        const int rl = wm2 + mi * 16 + fr4 + rr;
        const float qnr = qns[rl], crr = crs[rl], bqr = bqms[rl], q2r = q2bs[rl];
        const bool rowok = (m0 + rl) < qlv;
        const int ri = mi * 4 + rr;
#pragma unroll
        for (int nj = 0; nj < 2; nj++) {
          const float sq = fmaxf(qnr + Aj[nj] + bqr * Bj[nj] + q2r * Cj[nj]
                                 - 2.0f * acc[mi][nj][rr], 1e-12f);
          const float x = -__builtin_amdgcn_sqrtf(sq) + crr - Dj[nj] + t12s[rl + gj[nj]];
          const float vv = (rowok && gj[nj] < klv) ? x : -1e9f;
          s_[ri] += exp2f(vv * L2E);
        }
      }
    }
  }

  // -------- lse merge: sum over the 16 fc lanes, then the 4 n-group waves --------
#pragma unroll
  for (int k2 = 1; k2 <= 8; k2 <<= 1) {
#pragma unroll
    for (int ri = 0; ri < 8; ri++) s_[ri] += __shfl_xor(s_[ri], k2, 64);
  }
  if (fc == 0) {
#pragma unroll
    for (int mi = 0; mi < 2; mi++)
#pragma unroll
      for (int rr = 0; rr < 4; rr++)
        lseb[w & 3][wm2 + mi * 16 + fr4 + rr] = s_[mi * 4 + rr];
  }
  __syncthreads();
  if (t < 128) {
    const float tot = (lseb[0][t] + lseb[1][t]) + (lseb[2][t] + lseb[3][t]);
    lsef[t] = (tot > 0.f) ? logf(tot) : (-1e9f + logf((float)TK));
  }
  __syncthreads();

  float lse_r[8];
#pragma unroll
  for (int mi = 0; mi < 2; mi++)
#pragma unroll
    for (int rr = 0; rr < 4; rr++)
      lse_r[mi * 4 + rr] = lsef[wm2 + mi * 16 + fr4 + rr];

  // -------- pass 1: recompute v, subtract lse, per-wave LDS stage, 128B-line stores --------
  float* wstw = wst[w];
  for (int nt = 0; nt < 8; nt++) {
    bf16x8 bfr[4][2];
#pragma unroll
    for (int kc = 0; kc < 4; kc++)
#pragma unroll
      for (int nj = 0; nj < 2; nj++)
        bfr[kc][nj] = *reinterpret_cast<const bf16x8*>(
            Zb + (long)(nt * 128 + wn2 + nj * 16 + fr) * QDP + kc * 32 + fk);

    floatx4 acc[2][2];
#pragma unroll
    for (int mi = 0; mi < 2; mi++)
#pragma unroll
      for (int nj = 0; nj < 2; nj++) acc[mi][nj] = (floatx4){0.f, 0.f, 0.f, 0.f};
#pragma unroll
    for (int kc = 0; kc < 4; kc++)
#pragma unroll
      for (int mi = 0; mi < 2; mi++)
#pragma unroll
        for (int nj = 0; nj < 2; nj++)
          acc[mi][nj] = __builtin_amdgcn_mfma_f32_16x16x32_bf16(af[kc][mi], bfr[kc][nj], acc[mi][nj], 0, 0, 0);

    int gj[2]; float Aj[2], Bj[2], Cj[2], Dj[2];
#pragma unroll
    for (int nj = 0; nj < 2; nj++) {
      gj[nj] = nt * 128 + wn2 + nj * 16 + fc;
      Aj[nj] = jA[gj[nj]]; Bj[nj] = jB[gj[nj]]; Cj[nj] = jC[gj[nj]]; Dj[nj] = jc1[gj[nj]];
    }

#pragma unroll
    for (int mi = 0; mi < 2; mi++) {
#pragma unroll
      for (int rr = 0; rr < 4; rr++) {
        const int rl = wm2 + mi * 16 + fr4 + rr;
        const float qnr = qns[rl], crr = crs[rl], bqr = bqms[rl], q2r = q2bs[rl];
        const bool rowok = (m0 + rl) < qlv;
        const float l = lse_r[mi * 4 + rr];
#pragma unroll
        for (int nj = 0; nj < 2; nj++) {
          const float sq = fmaxf(qnr + Aj[nj] + bqr * Bj[nj] + q2r * Cj[nj]
                                 - 2.0f * acc[mi][nj][rr], 1e-12f);
          const float x = -__builtin_amdgcn_sqrtf(sq) + crr - Dj[nj] + t12s[rl + gj[nj]];
          const float vv = (rowok && gj[nj] < klv) ? x : -1e9f;
          wstw[(mi * 16 + fr4 + rr) * 36 + nj * 16 + fc] = vv - l;
        }
      }
    }

    // flush: each store instr = 8 rows x 32 cols -> 8 full 128B lines
#pragma unroll
    for (int st = 0; st < 4; st++) {
      const int lr2 = st * 8 + (lane >> 3);
      const int lc2 = (lane & 7) << 2;
      *reinterpret_cast<float4*>(outp + (long)(wm2 + lr2) * TK + nt * 128 + wn2 + lc2) =
          *reinterpret_cast<const float4*>(&wstw[lr2 * 36 + lc2]);
    }
  }
}

// ---------------- host ----------------
extern "C" void kernel_launch(void* const* d_in, const int* in_sizes, int n_in,
                              void* d_out, int out_size, void* d_ws, size_t ws_size,
                              hipStream_t stream)
{
  (void)in_sizes; (void)n_in; (void)out_size; (void)ws_size;
  const float* query = (const float*)d_in[0];
  const float* key   = (const float*)d_in[1];
  const int*   qlens = (const int*)d_in[2];
  const int*   klens = (const int*)d_in[3];
  const float* qc1_w = (const float*)d_in[4];
  const float* qc1_b = (const float*)d_in[5];
  const float* qc2_w = (const float*)d_in[6];
  const float* qc2_b = (const float*)d_in[7];
  const float* ql_w  = (const float*)d_in[8];
  const float* ql_b  = (const float*)d_in[9];
  const float* kc_w  = (const float*)d_in[10];
  const float* kc_b  = (const float*)d_in[11];
  const float* kl1_w = (const float*)d_in[12];
  const float* kl1_b = (const float*)d_in[13];
  const float* kl2_w = (const float*)d_in[14];
  const float* kl2_b = (const float*)d_in[15];

  size_t off = 0;
  char* ws = (char*)d_ws;
  auto alloc = [&](size_t bytes) -> char* {
    char* p = ws + off; off += (bytes + 255) & ~(size_t)255; return p;
  };
  // Front region (all dead by step 10): pool0 + qlw2 + kcp + TpT + pool = 69.2 MB
  u16* qc2w_bf = (u16*)alloc(2ull * H2 * H2);        //  8.39 MB
  u16* qc1T_bf = (u16*)alloc(2ull * QDP * H2);       //  0.52 MB
  u16* kl2w_bf = (u16*)alloc(2ull * HH * H2);        //  4.19 MB
  u16* kl1T_bf = (u16*)alloc(2ull * HH * H2);        //  4.19 MB
  u16* qT_bf   = (u16*)alloc(2ull * BB * QDP * 2048);//  8.39 MB   [pool0 = 25.69 MB]
  u16* kcolT_bf= (u16*)d_ws;                         // 25.17 MB overlay of pool0 (dead after X-GEMM)
  u16* Z2_bf   = (u16*)d_ws;                         //  4.19 MB overlay at front (written step 8)
  u16* qlw2_bf = (u16*)alloc(2ull * HH * 2048);      //  4.19 MB
  u16* kcp_bf  = (u16*)alloc(2ull * HH * 768);       //  1.57 MB
  u16* TpT_bf  = (u16*)alloc(2ull * H2 * HH);        //  4.19 MB  (rows = b*128+d, cols h)
  char* pool   = alloc(2ull * BB * HH * NKEY);       // 33.55 MB: split-K partials / X
  float* Pbuf  = (float*)pool;                       // fp32 partials (max 33.5 MB)
  u16* X_bf    = (u16*)pool;                         // X[b] (1024h x 768r) bf16, 25.2 MB
  // Region B: persistent through step 10
  float* tbl  = (float*)alloc(4ull * 8192);
  u16* Wq_bf  = (u16*)alloc(2ull * H2 * QDP);
  u16* Wk_bf  = (u16*)alloc(2ull * HH * NKEY);
  float* bqm  = (float*)alloc(4ull * H2);
  float* bkv  = (float*)alloc(4ull * HH);
  float* s1v  = (float*)alloc(4ull * HH);
  float* s0v  = (float*)alloc(4ull * HH);
  float* wsum = (float*)alloc(4ull * HH);
  float* colsum1 = (float*)alloc(4ull * H2);
  u16* K3_bf  = (u16*)alloc(2ull * BB * TK * HH);    // 33.55 MB
  float* qnv  = (float*)alloc(4ull * BB * TQ);
  float* knv  = (float*)alloc(4ull * BB * TK);
  float* ybv  = (float*)alloc(4ull * BB * TK);
  float* y1v  = (float*)alloc(4ull * BB * TK);
  float* y0v  = (float*)alloc(4ull * BB * TK);
  float* u0v  = (float*)alloc(4ull * BB * QDP);
  float* u1v  = (float*)alloc(4ull * BB * QDP);
  float* u2v  = (float*)alloc(4ull * BB * QDP);
  float* c1v  = (float*)alloc(4ull * BB * TK);
  float* crowv= (float*)alloc(4ull * BB * TQ);
  float* t12v = (float*)alloc(4ull * BB * T12N);
  float* scv  = (float*)alloc(256);
  // Parked in d_out (consumed by step 6, before step 10 overwrites d_out):
  float* WqG  = (float*)d_out;                              // 16.78 MB fp32
  u16* G_bf   = (u16*)((char*)d_out + 16777216);            //  0.52 MB

  // 1. prep (casts, qlw2, kcp, colsum, lgamma) + tiled transposes + bias folds
  prep_all_k<<<37920, 256, 0, stream>>>(qc2_w, kl2_w, ql_w, kc_w, kl1_w,
                                        qc2w_bf, kl2w_bf, qlw2_bf, kcp_bf, colsum1, tbl);
  tpack_k<<<1600, 256, 0, stream>>>(kl1_w, qc1_w, query, kl1T_bf, qc1T_bf, qT_bf);
  fold_bias_k<<<4096, 256, 0, stream>>>(qc2_w, qc1_b, qc2_b, kl2_w, kl1_b, kl2_b, ql_w, colsum1,
                                        bqm, bkv, s1v, s0v, wsum);

  // 2. Wq = qc2_w @ qc1_w-fold (2048x128), split-K 16 (KS=128)
  gemm_bt<1><<<dim3(1, 16, 16), 256, 0, stream>>>(qc2w_bf, qc1T_bf, Pbuf, H2, QDP, 128,
      H2, H2, 0, 16, 0, 0, (long)H2 * QDP, 0,
      nullptr, nullptr, nullptr, nullptr, nullptr, nullptr);
  reduce_bk_k<<<256, 256, 0, stream>>>(Pbuf, Wq_bf, (long)H2 * QDP, 16, (long)H2 * QDP);

  // 3. Wk = kl2_w @ kl1_w-fold (1024x1024), split-K 8 (KS=256)
  gemm_bt<1><<<dim3(8, 8, 8), 256, 0, stream>>>(kl2w_bf, kl1T_bf, Pbuf, HH, NKEY, 256,
      H2, H2, 0, 8, 0, 0, (long)HH * NKEY, 0,
      nullptr, nullptr, nullptr, nullptr, nullptr, nullptr);
  reduce_bk_k<<<1024, 256, 0, stream>>>(Pbuf, Wk_bf, (long)HH * NKEY, 8, (long)HH * NKEY);

  // 4. TpT (2048 x 1024) = qT @ qlw2^T, split-K 4 (KS=512)
  gemm_bt<1><<<dim3(8, 16, 4), 256, 0, stream>>>(qT_bf, qlw2_bf, Pbuf, H2, HH, 512,
      2048, 2048, 0, 4, 0, 0, (long)H2 * HH, 0,
      nullptr, nullptr, nullptr, nullptr, nullptr, nullptr);
  reduce_bk_k<<<2048, 256, 0, stream>>>(Pbuf, TpT_bf, (long)H2 * HH, 4, (long)H2 * HH);

  // 5. G[b] = TpT_b @ TpT_b^T (128x128 Gram per batch), split-K 8 (KS=128)
  gemm_bt<1><<<dim3(1, 1, 128), 256, 0, stream>>>(TpT_bf, TpT_bf, Pbuf, 128, 128, 128,
      HH, HH, 0, 8, (long)QDP * HH, (long)QDP * HH, 128 * 128, 0,
      nullptr, nullptr, nullptr, nullptr, nullptr, nullptr);
  reduce_bk_k<<<256, 256, 0, stream>>>(Pbuf, G_bf, 128 * 128, 8, (long)BB * 128 * 128);

  // 6. WqG[b] = Wq @ G[b]  (fp32, G symmetric) ; u-vectors + scalars + prior tables ; qn
  gemm_bt<1><<<dim3(1, 16, 16), 256, 0, stream>>>(Wq_bf, G_bf, WqG, H2, QDP, QDP,
      QDP, QDP, 0, 1, 0, (long)QDP * QDP, (long)H2 * QDP, 0,
      nullptr, nullptr, nullptr, nullptr, nullptr, nullptr);
  u_k<<<BB * QDP + 6 + 64 + 128 + 192, 256, 0, stream>>>(TpT_bf, ql_b, s1v, s0v, tbl, qlens, klens,
                                                         u0v, u1v, u2v, scv, c1v, crowv, t12v);
  qn_k<<<BB * TQ / 2, 256, 0, stream>>>(Wq_bf, WqG, u0v, u1v, u2v, bqm, qc2_b, scv, qnv);

  // 7. key branch, reassociated: X[b] = Wk @ kcolT[b]^T ; K3[b] = kcp @ X[b]^T + biases
  pack_kcolT_k<<<1024, 256, 0, stream>>>(key, kcolT_bf);
  gemm_bt<0><<<dim3(6, 8, BB), 256, 0, stream>>>(Wk_bf, kcolT_bf, X_bf, HH, 768, NKEY,
      NKEY, NKEY, 0, 1, 0, (long)768 * NKEY, (long)HH * 768, 0,
      nullptr, nullptr, nullptr, nullptr, nullptr, nullptr);
  gemm_bt<0><<<dim3(8, 8, BB), 256, 0, stream>>>(kcp_bf, X_bf, K3_bf, HH, NKEY, 768,
      768, 768, 1, 1, 0, (long)HH * 768, (long)TK * HH, 0,
      bkv, nullptr, kc_b, wsum, nullptr, nullptr);

  // 8. Z2[b] = K3[b] @ TpT_b^T (1024x128), split-K 2 (KS=512) -> Pbuf -> bf16 at d_ws front
  gemm_bt<1><<<dim3(8, 1, 32), 256, 0, stream>>>(K3_bf, TpT_bf, Pbuf, TK, QDP, 512,
      HH, HH, 1, 2, (long)TK * HH, (long)QDP * HH, (long)TK * QDP, 0,
      nullptr, nullptr, nullptr, nullptr, nullptr, nullptr);
  reduce_bk_k<<<2048, 256, 0, stream>>>(Pbuf, Z2_bf, (long)TK * QDP, 2, (long)BB * TK * QDP);

  // 9. K3 row norms + per-row bias dots (yb, y1, y0)
  rownormk_k<<<BB * TK, 256, 0, stream>>>(K3_bf, ql_b, s1v, s0v, knv, ybv, y1v, y0v);

  // 10. fused S-GEMM + dist + prior + log_softmax -> d_out (fp32), no intermediate
  //     grid (b, mt): all mt-blocks of batch b land on XCD b%8 -> Z2[b] L2-resident.
  smax_k<<<dim3(16, 16), 1024, 0, stream>>>(Wq_bf, Z2_bf, (float*)d_out,
      ybv, y1v, y0v, bqm, qc2_b, qnv, knv, c1v, crowv, t12v, qlens, klens);
}